// Round 2
// baseline (1664.457 us; speedup 1.0000x reference)
//
#include <hip/hip_runtime.h>
#include <hip/hip_bf16.h>
#include <cstddef>

#define BB 4
#define LQ 256
#define NS 24
#define NT 128
#define DD 512
#define HH 8
#define DKK 64
// scale = DK^-0.5 = 0.125

// ---------------- generic fp32 GEMM: C[M,512] = A[M,K] @ W[K,512] + bias ----------------
// block 256 threads, 64x64 tile, BK=16, each thread 4x4.
__global__ __launch_bounds__(256) void gemm_f32(
    const float* __restrict__ A, const float* __restrict__ W,
    const float* __restrict__ bias, float* __restrict__ C,
    int M, int K, int ldc, int coloff)
{
    __shared__ float As[16][64];  // [k][m]
    __shared__ float Ws[16][64];  // [k][n]
    const int bm = blockIdx.x * 64;
    const int bn = blockIdx.y * 64;
    const int tid = threadIdx.x;
    const int tx = tid & 15, ty = tid >> 4;
    const int ar = tid >> 2;           // 0..63
    const int ak = (tid & 3) * 4;      // 0,4,8,12
    const int wk = tid >> 4;           // 0..15
    const int wn = (tid & 15) * 4;     // 0..60
    float acc[4][4] = {};
    for (int k0 = 0; k0 < K; k0 += 16) {
        float4 av = make_float4(0.f, 0.f, 0.f, 0.f);
        if (bm + ar < M) av = *(const float4*)(A + (size_t)(bm + ar) * K + k0 + ak);
        As[ak + 0][ar] = av.x; As[ak + 1][ar] = av.y;
        As[ak + 2][ar] = av.z; As[ak + 3][ar] = av.w;
        float4 wv = *(const float4*)(W + (size_t)(k0 + wk) * 512 + bn + wn);
        *(float4*)&Ws[wk][wn] = wv;
        __syncthreads();
#pragma unroll
        for (int kk = 0; kk < 16; ++kk) {
            float4 a = *(const float4*)&As[kk][ty * 4];
            float4 w = *(const float4*)&Ws[kk][tx * 4];
            acc[0][0] += a.x * w.x; acc[0][1] += a.x * w.y; acc[0][2] += a.x * w.z; acc[0][3] += a.x * w.w;
            acc[1][0] += a.y * w.x; acc[1][1] += a.y * w.y; acc[1][2] += a.y * w.z; acc[1][3] += a.y * w.w;
            acc[2][0] += a.z * w.x; acc[2][1] += a.z * w.y; acc[2][2] += a.z * w.z; acc[2][3] += a.z * w.w;
            acc[3][0] += a.w * w.x; acc[3][1] += a.w * w.y; acc[3][2] += a.w * w.z; acc[3][3] += a.w * w.w;
        }
        __syncthreads();
    }
    float4 bv = *(const float4*)(bias + bn + tx * 4);
#pragma unroll
    for (int i = 0; i < 4; ++i) {
        int r = bm + ty * 4 + i;
        if (r < M) {
            float4 o;
            o.x = acc[i][0] + bv.x; o.y = acc[i][1] + bv.y;
            o.z = acc[i][2] + bv.z; o.w = acc[i][3] + bv.w;
            *(float4*)(C + (size_t)r * ldc + coloff + bn + tx * 4) = o;
        }
    }
}

// ---------------- sentence-level graph attention ----------------
// one wave per (b,h,q); block = 4 waves.
__global__ __launch_bounds__(256) void sent_attn(
    const float* __restrict__ qs, const float* __restrict__ ksb,
    const float* __restrict__ vsb, const float* __restrict__ bias_s,
    const float* __restrict__ gab, float* __restrict__ attns,
    float* __restrict__ ctxs)
{
    const int wid = blockIdx.x * 4 + (threadIdx.x >> 6);   // 0..8191
    const int lane = threadIdx.x & 63;
    const int q = wid & (LQ - 1);
    const int bh = wid >> 8;       // b*H+h
    const int h = bh & 7;
    const int b = bh >> 3;

    float qv = qs[(size_t)(b * LQ + q) * 512 + h * 64 + lane] * 0.125f;

    // scores: 24 wave reductions; lane ss keeps score[ss]
    float sc = 0.f;
#pragma unroll
    for (int ss = 0; ss < NS; ++ss) {
        float r = qv * ksb[(size_t)(b * NS + ss) * 512 + h * 64 + lane];
#pragma unroll
        for (int off = 32; off; off >>= 1) r += __shfl_xor(r, off);
        if (lane == ss) sc = r;
    }
    float val = (lane < NS)
        ? sc + bias_s[((size_t)(b * HH + h) * LQ + q) * NS + lane]
        : -1e30f;

    // softmax #1
    float m = val;
#pragma unroll
    for (int off = 32; off; off >>= 1) m = fmaxf(m, __shfl_xor(m, off));
    float p = __expf(val - m);
    float sum = p;
#pragma unroll
    for (int off = 32; off; off >>= 1) sum += __shfl_xor(sum, off);
    p /= sum;

    // graph prior: g[t] = sum_s p[s]*gab[b,h,s,t]
    const int tcl = (lane < NS) ? lane : (NS - 1);
    const float* gb = gab + (size_t)(b * HH + h) * NS * NS;
    float g = 0.f;
#pragma unroll
    for (int ss = 0; ss < NS; ++ss) {
        float ps = __shfl(p, ss);
        g += ps * gb[ss * NS + tcl];
    }
    float val2 = val - 0.5f * g * g;   // /((0.5*POS_WIN)^2)=1

    // softmax #2
    float m2 = val2;
#pragma unroll
    for (int off = 32; off; off >>= 1) m2 = fmaxf(m2, __shfl_xor(m2, off));
    float a = __expf(val2 - m2);
    float sum2 = a;
#pragma unroll
    for (int off = 32; off; off >>= 1) sum2 += __shfl_xor(sum2, off);
    a /= sum2;

    if (lane < NS)
        attns[((size_t)(b * HH + h) * LQ + q) * NS + lane] = a;

    // ctx_s row
    float ctx = 0.f;
#pragma unroll
    for (int ss = 0; ss < NS; ++ss) {
        float as = __shfl(a, ss);
        ctx += as * vsb[(size_t)(b * NS + ss) * 512 + h * 64 + lane];
    }
    ctxs[(size_t)(b * LQ + q) * 512 + h * 64 + lane] = ctx;
}

// ---------------- word-level attention, partials over s ----------------
// block per (b,s,h): stage K^T and V in LDS, loop 256 q rows (64 per wave).
// Partials are written IN-PLACE over the (now dead) h-columns of kwb/vwb rows
// for this (b,s): q<128 -> kwb row q, q>=128 -> vwb row q-128. Safe: this block
// staged exactly those bytes into LDS before the sync; other blocks (other h)
// touch disjoint columns.
__global__ __launch_bounds__(256) void word_attn(
    const float* __restrict__ qwb, float* __restrict__ kwb,
    float* __restrict__ vwb, const float* __restrict__ bias_w,
    const float* __restrict__ attns)
{
    __shared__ float kldsT[DKK][NT];   // [d][t]
    __shared__ float vlds[NT][DKK];    // [t][d]
    const int bid = blockIdx.x;        // (b*NS + s)*H + h
    const int h = bid & 7;
    const int tmp = bid >> 3;
    const int s = tmp % NS;
    const int b = tmp / NS;

    for (int i = threadIdx.x; i < NT * (DKK / 4); i += 256) {
        int t = i >> 4;
        int c = (i & 15) * 4;
        size_t goff = ((size_t)((b * NS + s) * NT + t)) * 512 + h * 64 + c;
        float4 kv = *(const float4*)(kwb + goff);
        float4 vv = *(const float4*)(vwb + goff);
        kldsT[c + 0][t] = kv.x; kldsT[c + 1][t] = kv.y;
        kldsT[c + 2][t] = kv.z; kldsT[c + 3][t] = kv.w;
        *(float4*)&vlds[t][c] = vv;
    }
    __syncthreads();

    const int lane = threadIdx.x & 63;
    const int wv = threadIdx.x >> 6;

    for (int qi = 0; qi < 64; ++qi) {
        const int q = wv * 64 + qi;
        float qv = qwb[(size_t)(b * LQ + q) * 512 + h * 64 + lane] * 0.125f;
        float s0 = 0.f, s1 = 0.f;
#pragma unroll
        for (int d = 0; d < 64; ++d) {
            float qd = __shfl(qv, d);
            s0 += qd * kldsT[d][lane];
            s1 += qd * kldsT[d][lane + 64];
        }
        size_t boff = ((((size_t)(b * NS + s) * HH + h) * LQ) + q) * NT + lane;
        s0 += bias_w[boff];
        s1 += bias_w[boff + 64];
        float mx = fmaxf(s0, s1);
#pragma unroll
        for (int off = 32; off; off >>= 1) mx = fmaxf(mx, __shfl_xor(mx, off));
        float p0 = __expf(s0 - mx), p1 = __expf(s1 - mx);
        float sm = p0 + p1;
#pragma unroll
        for (int off = 32; off; off >>= 1) sm += __shfl_xor(sm, off);
        float fac = attns[((size_t)(b * HH + h) * LQ + q) * NS + s] / sm;
        p0 *= fac; p1 *= fac;
        float o0 = 0.f, o1 = 0.f;
#pragma unroll
        for (int tt = 0; tt < 64; ++tt) {
            float b0 = __shfl(p0, tt);
            float b1 = __shfl(p1, tt);
            o0 += b0 * vlds[tt][lane];
            o1 += b1 * vlds[tt + 64][lane];
        }
        // partial for (b,s,h,q,d=lane) aliased over kwb/vwb
        float* dst = ((q < 128) ? kwb : vwb)
                   + ((size_t)((b * NS + s) * NT) + (q & 127)) * 512 + h * 64 + lane;
        *dst = o0 + o1;
    }
}

// ---------------- reduce partials over s (reads the kwb/vwb alias) ----------------
__global__ __launch_bounds__(256) void reduce_s(
    const float* __restrict__ kwb, const float* __restrict__ vwb,
    float* __restrict__ ctxw)
{
    int idx = blockIdx.x * 256 + threadIdx.x;   // B*H*LQ*DK = 524288
    int d = idx & 63;
    int q = (idx >> 6) & 255;
    int h = (idx >> 14) & 7;
    int b = idx >> 17;
    const float* base = ((q < 128) ? kwb : vwb)
                      + ((size_t)(b * NS) * NT + (q & 127)) * 512 + h * 64 + d;
    float acc = 0.f;
#pragma unroll
    for (int ss = 0; ss < NS; ++ss) acc += base[(size_t)ss * NT * 512];
    ctxw[((size_t)(b * LQ + q)) * 512 + h * 64 + d] = acc;
}

extern "C" void kernel_launch(void* const* d_in, const int* in_sizes, int n_in,
                              void* d_out, int out_size, void* d_ws, size_t ws_size,
                              hipStream_t stream) {
    const float* q_in   = (const float*)d_in[0];
    const float* k_s    = (const float*)d_in[1];
    const float* v_s    = (const float*)d_in[2];
    const float* k_w    = (const float*)d_in[3];
    const float* v_w    = (const float*)d_in[4];
    const float* bias_w = (const float*)d_in[5];
    const float* bias_s = (const float*)d_in[6];
    const float* gab    = (const float*)d_in[7];
    const float* wq_s = (const float*)d_in[8];
    const float* wk_s = (const float*)d_in[9];
    const float* wv_s = (const float*)d_in[10];
    const float* wq_w = (const float*)d_in[11];
    const float* wk_w = (const float*)d_in[12];
    const float* wv_w = (const float*)d_in[13];
    const float* fcs_w = (const float*)d_in[14];
    const float* fcw_w = (const float*)d_in[15];
    const float* bq_s = (const float*)d_in[16];
    const float* bk_s = (const float*)d_in[17];
    const float* bv_s = (const float*)d_in[18];
    const float* bq_w = (const float*)d_in[19];
    const float* bk_w = (const float*)d_in[20];
    const float* bv_w = (const float*)d_in[21];
    const float* fcs_b = (const float*)d_in[22];
    const float* fcw_b = (const float*)d_in[23];
    const float* fco_w = (const float*)d_in[24];
    const float* fco_b = (const float*)d_in[25];
    float* out = (float*)d_out;

    float* ws = (float*)d_ws;
    float* qs    = ws;                    // 524288  [B,LQ,512]
    float* ksb   = qs + 524288;           // 49152   [B,NS,512]
    float* vsb   = ksb + 49152;           // 49152
    float* qwb   = vsb + 49152;           // 524288
    float* kwb   = qwb + 524288;          // 6291456 [B,NS,NT,512]
    float* vwb   = kwb + 6291456;         // 6291456
    float* attns = vwb + 6291456;         // 196608  [B,H,LQ,NS]
    float* ctxs  = attns + 196608;        // 524288  [B,LQ,512]
    float* ctxw  = ctxs + 524288;         // 524288  [B,LQ,512]
    // total: 14,974,976 floats ~ 60 MB
    float* cat   = kwb;                   // alias: kwb (and its part-alias) dead after reduce_s

    dim3 blk(256);
    // projections
    gemm_f32<<<dim3(16, 8), blk, 0, stream>>>(q_in, wq_s, bq_s, qs, 1024, 512, 512, 0);
    gemm_f32<<<dim3(2, 8),  blk, 0, stream>>>(k_s, wk_s, bk_s, ksb, 96, 512, 512, 0);
    gemm_f32<<<dim3(2, 8),  blk, 0, stream>>>(v_s, wv_s, bv_s, vsb, 96, 512, 512, 0);
    gemm_f32<<<dim3(16, 8), blk, 0, stream>>>(q_in, wq_w, bq_w, qwb, 1024, 512, 512, 0);
    gemm_f32<<<dim3(192, 8), blk, 0, stream>>>(k_w, wk_w, bk_w, kwb, 12288, 512, 512, 0);
    gemm_f32<<<dim3(192, 8), blk, 0, stream>>>(v_w, wv_w, bv_w, vwb, 12288, 512, 512, 0);
    // sentence attention
    sent_attn<<<2048, blk, 0, stream>>>(qs, ksb, vsb, bias_s, gab, attns, ctxs);
    // word attention partials (aliased over kwb/vwb) + reduce
    word_attn<<<BB * NS * HH, blk, 0, stream>>>(qwb, kwb, vwb, bias_w, attns);
    reduce_s<<<2048, blk, 0, stream>>>(kwb, vwb, ctxw);
    // output projections (cat aliases kwb — safe after reduce_s)
    gemm_f32<<<dim3(16, 8), blk, 0, stream>>>(ctxs, fcs_w, fcs_b, cat, 1024, 512, 1024, 0);
    gemm_f32<<<dim3(16, 8), blk, 0, stream>>>(ctxw, fcw_w, fcw_b, cat, 1024, 512, 1024, 512);
    gemm_f32<<<dim3(16, 8), blk, 0, stream>>>(cat, fco_w, fco_b, out, 1024, 1024, 512, 0);
}

// Round 3
// 799.112 us; speedup vs baseline: 2.0829x; 2.0829x over previous
//
#include <hip/hip_runtime.h>
#include <hip/hip_bf16.h>
#include <cstddef>

#define BB 4
#define LQ 256
#define NS 24
#define NT 128
#define DD 512
#define HH 8
#define DKK 64
// scale = DK^-0.5 = 0.125

typedef short short8v __attribute__((ext_vector_type(8)));   // 8 bf16 in 4 VGPRs
typedef float f32x4 __attribute__((ext_vector_type(4)));

__device__ __forceinline__ unsigned short f2bf(float f) {
    unsigned u = __float_as_uint(f);
    return (unsigned short)((u + 0x7fffu + ((u >> 16) & 1u)) >> 16);
}

// ---------------- generic fp32 GEMM: C[M,512] = A[M,K] @ W[K,512] + bias ----------------
__global__ __launch_bounds__(256) void gemm_f32(
    const float* __restrict__ A, const float* __restrict__ W,
    const float* __restrict__ bias, float* __restrict__ C,
    int M, int K, int ldc, int coloff)
{
    __shared__ float As[16][64];
    __shared__ float Ws[16][64];
    const int bm = blockIdx.x * 64;
    const int bn = blockIdx.y * 64;
    const int tid = threadIdx.x;
    const int tx = tid & 15, ty = tid >> 4;
    const int ar = tid >> 2;
    const int ak = (tid & 3) * 4;
    const int wk = tid >> 4;
    const int wn = (tid & 15) * 4;
    float acc[4][4] = {};
    for (int k0 = 0; k0 < K; k0 += 16) {
        float4 av = make_float4(0.f, 0.f, 0.f, 0.f);
        if (bm + ar < M) av = *(const float4*)(A + (size_t)(bm + ar) * K + k0 + ak);
        As[ak + 0][ar] = av.x; As[ak + 1][ar] = av.y;
        As[ak + 2][ar] = av.z; As[ak + 3][ar] = av.w;
        float4 wv = *(const float4*)(W + (size_t)(k0 + wk) * 512 + bn + wn);
        *(float4*)&Ws[wk][wn] = wv;
        __syncthreads();
#pragma unroll
        for (int kk = 0; kk < 16; ++kk) {
            float4 a = *(const float4*)&As[kk][ty * 4];
            float4 w = *(const float4*)&Ws[kk][tx * 4];
            acc[0][0] += a.x * w.x; acc[0][1] += a.x * w.y; acc[0][2] += a.x * w.z; acc[0][3] += a.x * w.w;
            acc[1][0] += a.y * w.x; acc[1][1] += a.y * w.y; acc[1][2] += a.y * w.z; acc[1][3] += a.y * w.w;
            acc[2][0] += a.z * w.x; acc[2][1] += a.z * w.y; acc[2][2] += a.z * w.z; acc[2][3] += a.z * w.w;
            acc[3][0] += a.w * w.x; acc[3][1] += a.w * w.y; acc[3][2] += a.w * w.z; acc[3][3] += a.w * w.w;
        }
        __syncthreads();
    }
    float4 bv = *(const float4*)(bias + bn + tx * 4);
#pragma unroll
    for (int i = 0; i < 4; ++i) {
        int r = bm + ty * 4 + i;
        if (r < M) {
            float4 o;
            o.x = acc[i][0] + bv.x; o.y = acc[i][1] + bv.y;
            o.z = acc[i][2] + bv.z; o.w = acc[i][3] + bv.w;
            *(float4*)(C + (size_t)r * ldc + coloff + bn + tx * 4) = o;
        }
    }
}

// ---------------- GEMM with bf16 output: Cb[M,512] (row-major bf16) ----------------
__global__ __launch_bounds__(256) void gemm_bf16(
    const float* __restrict__ A, const float* __restrict__ W,
    const float* __restrict__ bias, unsigned short* __restrict__ Cb, int M)
{
    __shared__ float As[16][64];
    __shared__ float Ws[16][64];
    const int bm = blockIdx.x * 64;
    const int bn = blockIdx.y * 64;
    const int tid = threadIdx.x;
    const int tx = tid & 15, ty = tid >> 4;
    const int ar = tid >> 2;
    const int ak = (tid & 3) * 4;
    const int wk = tid >> 4;
    const int wn = (tid & 15) * 4;
    float acc[4][4] = {};
    for (int k0 = 0; k0 < 512; k0 += 16) {
        float4 av = *(const float4*)(A + (size_t)(bm + ar) * 512 + k0 + ak);
        As[ak + 0][ar] = av.x; As[ak + 1][ar] = av.y;
        As[ak + 2][ar] = av.z; As[ak + 3][ar] = av.w;
        float4 wv = *(const float4*)(W + (size_t)(k0 + wk) * 512 + bn + wn);
        *(float4*)&Ws[wk][wn] = wv;
        __syncthreads();
#pragma unroll
        for (int kk = 0; kk < 16; ++kk) {
            float4 a = *(const float4*)&As[kk][ty * 4];
            float4 w = *(const float4*)&Ws[kk][tx * 4];
            acc[0][0] += a.x * w.x; acc[0][1] += a.x * w.y; acc[0][2] += a.x * w.z; acc[0][3] += a.x * w.w;
            acc[1][0] += a.y * w.x; acc[1][1] += a.y * w.y; acc[1][2] += a.y * w.z; acc[1][3] += a.y * w.w;
            acc[2][0] += a.z * w.x; acc[2][1] += a.z * w.y; acc[2][2] += a.z * w.z; acc[2][3] += a.z * w.w;
            acc[3][0] += a.w * w.x; acc[3][1] += a.w * w.y; acc[3][2] += a.w * w.z; acc[3][3] += a.w * w.w;
        }
        __syncthreads();
    }
    float4 bv = *(const float4*)(bias + bn + tx * 4);
#pragma unroll
    for (int i = 0; i < 4; ++i) {
        int r = bm + ty * 4 + i;
        ushort4 u;
        u.x = f2bf(acc[i][0] + bv.x); u.y = f2bf(acc[i][1] + bv.y);
        u.z = f2bf(acc[i][2] + bv.z); u.w = f2bf(acc[i][3] + bv.w);
        *(ushort4*)(Cb + (size_t)r * 512 + bn + tx * 4) = u;
    }
}

// ---------------- GEMM with TRANSPOSED bf16 output: CT[512, M] ----------------
__global__ __launch_bounds__(256) void gemm_bf16T(
    const float* __restrict__ A, const float* __restrict__ W,
    const float* __restrict__ bias, unsigned short* __restrict__ CT, int M)
{
    __shared__ float As[16][64];
    __shared__ float Ws[16][64];
    const int bm = blockIdx.x * 64;
    const int bn = blockIdx.y * 64;
    const int tid = threadIdx.x;
    const int tx = tid & 15, ty = tid >> 4;
    const int ar = tid >> 2;
    const int ak = (tid & 3) * 4;
    const int wk = tid >> 4;
    const int wn = (tid & 15) * 4;
    float acc[4][4] = {};
    for (int k0 = 0; k0 < 512; k0 += 16) {
        float4 av = *(const float4*)(A + (size_t)(bm + ar) * 512 + k0 + ak);
        As[ak + 0][ar] = av.x; As[ak + 1][ar] = av.y;
        As[ak + 2][ar] = av.z; As[ak + 3][ar] = av.w;
        float4 wv = *(const float4*)(W + (size_t)(k0 + wk) * 512 + bn + wn);
        *(float4*)&Ws[wk][wn] = wv;
        __syncthreads();
#pragma unroll
        for (int kk = 0; kk < 16; ++kk) {
            float4 a = *(const float4*)&As[kk][ty * 4];
            float4 w = *(const float4*)&Ws[kk][tx * 4];
            acc[0][0] += a.x * w.x; acc[0][1] += a.x * w.y; acc[0][2] += a.x * w.z; acc[0][3] += a.x * w.w;
            acc[1][0] += a.y * w.x; acc[1][1] += a.y * w.y; acc[1][2] += a.y * w.z; acc[1][3] += a.y * w.w;
            acc[2][0] += a.z * w.x; acc[2][1] += a.z * w.y; acc[2][2] += a.z * w.z; acc[2][3] += a.z * w.w;
            acc[3][0] += a.w * w.x; acc[3][1] += a.w * w.y; acc[3][2] += a.w * w.z; acc[3][3] += a.w * w.w;
        }
        __syncthreads();
    }
    float4 bv = *(const float4*)(bias + bn + tx * 4);
    const float bj[4] = {bv.x, bv.y, bv.z, bv.w};
#pragma unroll
    for (int j = 0; j < 4; ++j) {
        int c = bn + tx * 4 + j;
        ushort4 u;
        u.x = f2bf(acc[0][j] + bj[j]); u.y = f2bf(acc[1][j] + bj[j]);
        u.z = f2bf(acc[2][j] + bj[j]); u.w = f2bf(acc[3][j] + bj[j]);
        *(ushort4*)(CT + (size_t)c * M + bm + ty * 4) = u;
    }
}

// ---------------- sentence-level graph attention (fp32, unchanged) ----------------
__global__ __launch_bounds__(256) void sent_attn(
    const float* __restrict__ qs, const float* __restrict__ ksb,
    const float* __restrict__ vsb, const float* __restrict__ bias_s,
    const float* __restrict__ gab, float* __restrict__ attns,
    float* __restrict__ ctxs)
{
    const int wid = blockIdx.x * 4 + (threadIdx.x >> 6);
    const int lane = threadIdx.x & 63;
    const int q = wid & (LQ - 1);
    const int bh = wid >> 8;
    const int h = bh & 7;
    const int b = bh >> 3;

    float qv = qs[(size_t)(b * LQ + q) * 512 + h * 64 + lane] * 0.125f;

    float sc = 0.f;
#pragma unroll
    for (int ss = 0; ss < NS; ++ss) {
        float r = qv * ksb[(size_t)(b * NS + ss) * 512 + h * 64 + lane];
#pragma unroll
        for (int off = 32; off; off >>= 1) r += __shfl_xor(r, off);
        if (lane == ss) sc = r;
    }
    float val = (lane < NS)
        ? sc + bias_s[((size_t)(b * HH + h) * LQ + q) * NS + lane]
        : -1e30f;

    float m = val;
#pragma unroll
    for (int off = 32; off; off >>= 1) m = fmaxf(m, __shfl_xor(m, off));
    float p = __expf(val - m);
    float sum = p;
#pragma unroll
    for (int off = 32; off; off >>= 1) sum += __shfl_xor(sum, off);
    p /= sum;

    const int tcl = (lane < NS) ? lane : (NS - 1);
    const float* gb = gab + (size_t)(b * HH + h) * NS * NS;
    float g = 0.f;
#pragma unroll
    for (int ss = 0; ss < NS; ++ss) {
        float ps = __shfl(p, ss);
        g += ps * gb[ss * NS + tcl];
    }
    float val2 = val - 0.5f * g * g;

    float m2 = val2;
#pragma unroll
    for (int off = 32; off; off >>= 1) m2 = fmaxf(m2, __shfl_xor(m2, off));
    float a = __expf(val2 - m2);
    float sum2 = a;
#pragma unroll
    for (int off = 32; off; off >>= 1) sum2 += __shfl_xor(sum2, off);
    a /= sum2;

    if (lane < NS)
        attns[((size_t)(b * HH + h) * LQ + q) * NS + lane] = a;

    float ctx = 0.f;
#pragma unroll
    for (int ss = 0; ss < NS; ++ss) {
        float as = __shfl(a, ss);
        ctx += as * vsb[(size_t)(b * NS + ss) * 512 + h * 64 + lane];
    }
    ctxs[(size_t)(b * LQ + q) * 512 + h * 64 + lane] = ctx;
}

// ---------------- word-level attention via MFMA ----------------
// grid 512: bid -> sp(0..3), qt(0..3), h(0..7), b(0..3). 4 waves, wave = 16 q rows.
// A/B frag layout for v_mfma_f32_16x16x32_bf16:
//   A: row = lane&15, k = (lane>>4)*8 + j (8 contiguous)
//   B: col = lane&15, k = (lane>>4)*8 + j (8 contiguous)
//   C/D: col = lane&15, row = (lane>>4)*4 + reg   [m89-verified]
__global__ __launch_bounds__(256) void word_attn_mfma(
    const unsigned short* __restrict__ qwb,   // [B*LQ, 512] bf16
    const unsigned short* __restrict__ kwb,   // [B*NS*NT, 512] bf16
    const unsigned short* __restrict__ vwbT,  // [512, B*NS*NT] bf16 (transposed)
    const float* __restrict__ bias_w,         // [B,NS,H,LQ,NT] fp32
    const float* __restrict__ attns,          // [B,H,LQ,NS] fp32
    float* __restrict__ part)                 // [4][B][H][LQ][64] fp32
{
    __shared__ __align__(16) unsigned short P_lds[4][16][136];  // per-wave P, +8 pad
    const int bid = blockIdx.x;
    const int sp = bid & 3;
    const int qt = (bid >> 2) & 3;
    const int h  = (bid >> 4) & 7;
    const int b  = bid >> 7;
    const int tid = threadIdx.x;
    const int wv = tid >> 6;
    const int l  = tid & 63;
    const int lr = l & 15;     // frag row/col index
    const int lg = l >> 4;     // k-group
    const int q0 = qt * 64 + wv * 16;
    const int MW = BB * NS * NT;   // 12288

    // hoisted Q A-frags (invariant over s)
    const unsigned short* qbase = qwb + (size_t)(b * LQ + q0 + lr) * 512 + h * 64 + lg * 8;
    short8v aq0 = *(const short8v*)(qbase);
    short8v aq1 = *(const short8v*)(qbase + 32);

    f32x4 out0 = {0.f,0.f,0.f,0.f}, out1 = out0, out2 = out0, out3 = out0;

    for (int si = 0; si < 6; ++si) {
        const int s = sp * 6 + si;
        // ---- scores: S[16q x 128t] = Q @ K^T ----
        f32x4 sc[8];
        const unsigned short* kbase = kwb + (size_t)((b * NS + s) * NT + lr) * 512 + h * 64 + lg * 8;
#pragma unroll
        for (int n = 0; n < 8; ++n) {
            const unsigned short* kp = kbase + (size_t)n * 16 * 512;
            short8v bk0 = *(const short8v*)(kp);
            short8v bk1 = *(const short8v*)(kp + 32);
            f32x4 z = {0.f,0.f,0.f,0.f};
            z = __builtin_amdgcn_mfma_f32_16x16x32_bf16(aq0, bk0, z, 0, 0, 0);
            sc[n] = __builtin_amdgcn_mfma_f32_16x16x32_bf16(aq1, bk1, z, 0, 0, 0);
        }
        // ---- bias + softmax + attns renorm (rows q = q0 + lg*4 + reg) ----
        const float* bb = bias_w + ((((size_t)(b * NS + s) * HH + h) * LQ) + q0 + lg * 4) * NT + lr;
#pragma unroll
        for (int reg = 0; reg < 4; ++reg) {
            float v0 = sc[0][reg] * 0.125f + bb[(size_t)reg * NT +   0];
            float v1 = sc[1][reg] * 0.125f + bb[(size_t)reg * NT +  16];
            float v2 = sc[2][reg] * 0.125f + bb[(size_t)reg * NT +  32];
            float v3 = sc[3][reg] * 0.125f + bb[(size_t)reg * NT +  48];
            float v4 = sc[4][reg] * 0.125f + bb[(size_t)reg * NT +  64];
            float v5 = sc[5][reg] * 0.125f + bb[(size_t)reg * NT +  80];
            float v6 = sc[6][reg] * 0.125f + bb[(size_t)reg * NT +  96];
            float v7 = sc[7][reg] * 0.125f + bb[(size_t)reg * NT + 112];
            float mx = fmaxf(fmaxf(fmaxf(v0, v1), fmaxf(v2, v3)),
                             fmaxf(fmaxf(v4, v5), fmaxf(v6, v7)));
            mx = fmaxf(mx, __shfl_xor(mx, 1));
            mx = fmaxf(mx, __shfl_xor(mx, 2));
            mx = fmaxf(mx, __shfl_xor(mx, 4));
            mx = fmaxf(mx, __shfl_xor(mx, 8));
            v0 = __expf(v0 - mx); v1 = __expf(v1 - mx); v2 = __expf(v2 - mx); v3 = __expf(v3 - mx);
            v4 = __expf(v4 - mx); v5 = __expf(v5 - mx); v6 = __expf(v6 - mx); v7 = __expf(v7 - mx);
            float sm = ((v0 + v1) + (v2 + v3)) + ((v4 + v5) + (v6 + v7));
            sm += __shfl_xor(sm, 1);
            sm += __shfl_xor(sm, 2);
            sm += __shfl_xor(sm, 4);
            sm += __shfl_xor(sm, 8);
            float at = attns[((size_t)(b * HH + h) * LQ + q0 + lg * 4 + reg) * NS + s];
            float fac = at / sm;
            const int qrow = lg * 4 + reg;
            P_lds[wv][qrow][  0 + lr] = f2bf(v0 * fac);
            P_lds[wv][qrow][ 16 + lr] = f2bf(v1 * fac);
            P_lds[wv][qrow][ 32 + lr] = f2bf(v2 * fac);
            P_lds[wv][qrow][ 48 + lr] = f2bf(v3 * fac);
            P_lds[wv][qrow][ 64 + lr] = f2bf(v4 * fac);
            P_lds[wv][qrow][ 80 + lr] = f2bf(v5 * fac);
            P_lds[wv][qrow][ 96 + lr] = f2bf(v6 * fac);
            P_lds[wv][qrow][112 + lr] = f2bf(v7 * fac);
        }
        // ---- PV: out[16q x 64d] += P @ V  (V^T rows contiguous over t) ----
        const unsigned short* vb = vwbT + (size_t)(h * 64 + lr) * MW + (size_t)(b * NS + s) * NT + lg * 8;
#pragma unroll
        for (int ks = 0; ks < 4; ++ks) {
            short8v pa = *(const short8v*)&P_lds[wv][lr][ks * 32 + lg * 8];
            const unsigned short* vk = vb + ks * 32;
            short8v bv0 = *(const short8v*)(vk);
            short8v bv1 = *(const short8v*)(vk + (size_t)16 * MW);
            short8v bv2 = *(const short8v*)(vk + (size_t)32 * MW);
            short8v bv3 = *(const short8v*)(vk + (size_t)48 * MW);
            out0 = __builtin_amdgcn_mfma_f32_16x16x32_bf16(pa, bv0, out0, 0, 0, 0);
            out1 = __builtin_amdgcn_mfma_f32_16x16x32_bf16(pa, bv1, out1, 0, 0, 0);
            out2 = __builtin_amdgcn_mfma_f32_16x16x32_bf16(pa, bv2, out2, 0, 0, 0);
            out3 = __builtin_amdgcn_mfma_f32_16x16x32_bf16(pa, bv3, out3, 0, 0, 0);
        }
    }
    // ---- write fp32 partial: part[sp][b][h][q][d] ----
    float* pp = part + ((((size_t)sp * BB + b) * HH + h) * LQ) * 64;
#pragma unroll
    for (int reg = 0; reg < 4; ++reg) {
        const size_t ro = (size_t)(q0 + lg * 4 + reg) * 64 + lr;
        pp[ro +  0] = out0[reg];
        pp[ro + 16] = out1[reg];
        pp[ro + 32] = out2[reg];
        pp[ro + 48] = out3[reg];
    }
}

// ---------------- reduce 4 s-partials -> ctxw [B,LQ,512] ----------------
__global__ __launch_bounds__(256) void reduce_part(
    const float* __restrict__ part, float* __restrict__ ctxw)
{
    int idx = blockIdx.x * 256 + threadIdx.x;   // 524288
    int d = idx & 63;
    int q = (idx >> 6) & 255;
    int h = (idx >> 14) & 7;
    int b = idx >> 17;
    size_t o = ((((size_t)b * HH + h) * LQ) + q) * 64 + d;
    const size_t stride = (size_t)BB * HH * LQ * 64;
    float acc = part[o] + part[o + stride] + part[o + 2 * stride] + part[o + 3 * stride];
    ctxw[((size_t)(b * LQ + q)) * 512 + h * 64 + d] = acc;
}

extern "C" void kernel_launch(void* const* d_in, const int* in_sizes, int n_in,
                              void* d_out, int out_size, void* d_ws, size_t ws_size,
                              hipStream_t stream) {
    const float* q_in   = (const float*)d_in[0];
    const float* k_s    = (const float*)d_in[1];
    const float* v_s    = (const float*)d_in[2];
    const float* k_w    = (const float*)d_in[3];
    const float* v_w    = (const float*)d_in[4];
    const float* bias_w = (const float*)d_in[5];
    const float* bias_s = (const float*)d_in[6];
    const float* gab    = (const float*)d_in[7];
    const float* wq_s = (const float*)d_in[8];
    const float* wk_s = (const float*)d_in[9];
    const float* wv_s = (const float*)d_in[10];
    const float* wq_w = (const float*)d_in[11];
    const float* wk_w = (const float*)d_in[12];
    const float* wv_w = (const float*)d_in[13];
    const float* fcs_w = (const float*)d_in[14];
    const float* fcw_w = (const float*)d_in[15];
    const float* bq_s = (const float*)d_in[16];
    const float* bk_s = (const float*)d_in[17];
    const float* bv_s = (const float*)d_in[18];
    const float* bq_w = (const float*)d_in[19];
    const float* bk_w = (const float*)d_in[20];
    const float* bv_w = (const float*)d_in[21];
    const float* fcs_b = (const float*)d_in[22];
    const float* fcw_b = (const float*)d_in[23];
    const float* fco_w = (const float*)d_in[24];
    const float* fco_b = (const float*)d_in[25];
    float* out = (float*)d_out;

    float* ws = (float*)d_ws;
    float* qs    = ws;                    // 524288
    float* ksb   = qs + 524288;           // 49152
    float* vsb   = ksb + 49152;           // 49152
    float* attns = vsb + 49152;           // 196608
    float* ctxs  = attns + 196608;        // 524288
    float* ctxw  = ctxs + 524288;         // 524288
    float* part  = ctxw + 524288;         // 4*524288 = 2097152
    float* cat   = part + 2097152;        // 1048576
    unsigned short* qwb  = (unsigned short*)(cat + 1048576);  // 524288 bf16
    unsigned short* kwb  = qwb + 524288;                      // 6291456 bf16
    unsigned short* vwbT = kwb + 6291456;                     // 6291456 bf16
    // total ~46.3 MB

    dim3 blk(256);
    // sentence-path projections (fp32)
    gemm_f32<<<dim3(16, 8), blk, 0, stream>>>(q_in, wq_s, bq_s, qs, 1024, 512, 512, 0);
    gemm_f32<<<dim3(2, 8),  blk, 0, stream>>>(k_s, wk_s, bk_s, ksb, 96, 512, 512, 0);
    gemm_f32<<<dim3(2, 8),  blk, 0, stream>>>(v_s, wv_s, bv_s, vsb, 96, 512, 512, 0);
    // word-path projections (bf16 outputs; V transposed)
    gemm_bf16 <<<dim3(16, 8),  blk, 0, stream>>>(q_in, wq_w, bq_w, qwb, 1024);
    gemm_bf16 <<<dim3(192, 8), blk, 0, stream>>>(k_w, wk_w, bk_w, kwb, 12288);
    gemm_bf16T<<<dim3(192, 8), blk, 0, stream>>>(v_w, wv_w, bv_w, vwbT, 12288);
    // sentence attention
    sent_attn<<<2048, blk, 0, stream>>>(qs, ksb, vsb, bias_s, gab, attns, ctxs);
    // word attention (MFMA) + reduce
    word_attn_mfma<<<512, blk, 0, stream>>>(qwb, kwb, vwbT, bias_w, attns, part);
    reduce_part<<<2048, blk, 0, stream>>>(part, ctxw);
    // output projections (fp32)
    gemm_f32<<<dim3(16, 8), blk, 0, stream>>>(ctxs, fcs_w, fcs_b, cat, 1024, 512, 1024, 0);
    gemm_f32<<<dim3(16, 8), blk, 0, stream>>>(ctxw, fcw_w, fcw_b, cat, 1024, 512, 1024, 512);
    gemm_f32<<<dim3(16, 8), blk, 0, stream>>>(cat, fco_w, fco_b, out, 1024, 1024, 512, 0);
}

// Round 4
// 523.388 us; speedup vs baseline: 3.1802x; 1.5268x over previous
//
#include <hip/hip_runtime.h>
#include <hip/hip_bf16.h>
#include <cstddef>

#define BB 4
#define LQ 256
#define NS 24
#define NT 128
#define DD 512
#define HH 8
#define DKK 64
// scale = DK^-0.5 = 0.125

typedef short short8v __attribute__((ext_vector_type(8)));   // 8 bf16 in 4 VGPRs
typedef float f32x4 __attribute__((ext_vector_type(4)));

__device__ __forceinline__ unsigned short f2bf(float f) {
    unsigned u = __float_as_uint(f);
    return (unsigned short)((u + 0x7fffu + ((u >> 16) & 1u)) >> 16);
}
__device__ __forceinline__ float bf2f(unsigned short u) {
    return __uint_as_float(((unsigned)u) << 16);
}

// ---------------- fused input casts: q, k_s, v_s, k_w, v_w -> bf16 ----------------
__global__ __launch_bounds__(256) void cast5(
    const float* __restrict__ q, const float* __restrict__ ks, const float* __restrict__ vs,
    const float* __restrict__ kw, const float* __restrict__ vw,
    unsigned short* __restrict__ qb, unsigned short* __restrict__ ksb,
    unsigned short* __restrict__ vsb, unsigned short* __restrict__ kwb,
    unsigned short* __restrict__ vwb)
{
    int t = blockIdx.x * 256 + threadIdx.x;   // each thread: 8 elements
    const float* src; unsigned short* dst; size_t i;
    if (t < 65536)        { src = q;  dst = qb;  i = (size_t)t * 8; }
    else if (t < 71680)   { src = ks; dst = ksb; i = (size_t)(t - 65536) * 8; }
    else if (t < 77824)   { src = vs; dst = vsb; i = (size_t)(t - 71680) * 8; }
    else if (t < 864256)  { src = kw; dst = kwb; i = (size_t)(t - 77824) * 8; }
    else                  { src = vw; dst = vwb; i = (size_t)(t - 864256) * 8; }
    float4 a = *(const float4*)(src + i);
    float4 b = *(const float4*)(src + i + 4);
    short8v o;
    o[0] = f2bf(a.x); o[1] = f2bf(a.y); o[2] = f2bf(a.z); o[3] = f2bf(a.w);
    o[4] = f2bf(b.x); o[5] = f2bf(b.y); o[6] = f2bf(b.z); o[7] = f2bf(b.w);
    *(short8v*)(dst + i) = o;
}

// ---------------- weight transpose-cast: WT[n][k] = bf16(W[k][n]), N=512 ----------------
struct WTArgs {
    const float* w[9];
    unsigned short* wt[9];
    int K[9];
};
__global__ __launch_bounds__(256) void wtrans(WTArgs a) {
    const int widx = blockIdx.z;
    const int K = a.K[widx];
    const int kt = blockIdx.x;
    if (kt * 64 >= K) return;
    const int nt = blockIdx.y;
    const float* W = a.w[widx];
    unsigned short* WT = a.wt[widx];
    __shared__ float T[64][65];
    const int tx = threadIdx.x & 63, ty = threadIdx.x >> 6;
    const int k0 = kt * 64, n0 = nt * 64;
#pragma unroll
    for (int r = 0; r < 16; ++r)
        T[ty * 16 + r][tx] = W[(size_t)(k0 + ty * 16 + r) * 512 + n0 + tx];
    __syncthreads();
#pragma unroll
    for (int r = 0; r < 16; ++r)
        WT[(size_t)(n0 + ty * 16 + r) * K + k0 + tx] = f2bf(T[tx][ty * 16 + r]);
}

// ---------------- MFMA GEMM: C[M,N=512] = A_bf16[M,K] @ WT_bf16[N,K]^T + bias ----------------
// MODE 0: f32 out [M,ldc] at coloff; MODE 1: bf16 out; MODE 2: bf16 transposed out CT[N][M].
// Frags (v_mfma_f32_16x16x32_bf16): A row=lane&15 k=(lane>>4)*8+j ; B col=lane&15 same k;
// C/D col=lane&15, row=(lane>>4)*4+reg  [m89-verified].
template<int MODE, int K>
__global__ __launch_bounds__(256) void gemm_mfma(
    const unsigned short* __restrict__ A, const unsigned short* __restrict__ WT,
    const float* __restrict__ bias, void* __restrict__ Cv, int M, int ldc, int coloff)
{
    const int wv = threadIdx.x >> 6;
    const int l  = threadIdx.x & 63;
    const int lr = l & 15, lg = l >> 4;
    const int m0 = blockIdx.x * 64 + wv * 16;
    const int n0 = blockIdx.y * 64;
    int arow = m0 + lr; if (arow >= M) arow = M - 1;
    const unsigned short* ap = A + (size_t)arow * K + lg * 8;
    const unsigned short* wp = WT + (size_t)(n0 + lr) * K + lg * 8;
    f32x4 acc[4];
#pragma unroll
    for (int n = 0; n < 4; ++n) acc[n] = (f32x4){0.f, 0.f, 0.f, 0.f};
#pragma unroll
    for (int k0 = 0; k0 < K; k0 += 32) {
        short8v a  = *(const short8v*)(ap + k0);
        short8v b0 = *(const short8v*)(wp + k0);
        short8v b1 = *(const short8v*)(wp + (size_t)16 * K + k0);
        short8v b2 = *(const short8v*)(wp + (size_t)32 * K + k0);
        short8v b3 = *(const short8v*)(wp + (size_t)48 * K + k0);
        acc[0] = __builtin_amdgcn_mfma_f32_16x16x32_bf16(a, b0, acc[0], 0, 0, 0);
        acc[1] = __builtin_amdgcn_mfma_f32_16x16x32_bf16(a, b1, acc[1], 0, 0, 0);
        acc[2] = __builtin_amdgcn_mfma_f32_16x16x32_bf16(a, b2, acc[2], 0, 0, 0);
        acc[3] = __builtin_amdgcn_mfma_f32_16x16x32_bf16(a, b3, acc[3], 0, 0, 0);
    }
    float bv[4];
#pragma unroll
    for (int n = 0; n < 4; ++n) bv[n] = bias[n0 + n * 16 + lr];

    if (MODE == 0) {
        float* C = (float*)Cv;
#pragma unroll
        for (int reg = 0; reg < 4; ++reg) {
            int row = m0 + lg * 4 + reg;
            if (row < M) {
#pragma unroll
                for (int n = 0; n < 4; ++n)
                    C[(size_t)row * ldc + coloff + n0 + n * 16 + lr] = acc[n][reg] + bv[n];
            }
        }
    } else if (MODE == 1) {
        unsigned short* C = (unsigned short*)Cv;
#pragma unroll
        for (int reg = 0; reg < 4; ++reg) {
            int row = m0 + lg * 4 + reg;
            if (row < M) {
#pragma unroll
                for (int n = 0; n < 4; ++n)
                    C[(size_t)row * ldc + coloff + n0 + n * 16 + lr] = f2bf(acc[n][reg] + bv[n]);
            }
        }
    } else {
        // transposed bf16 out CT[N][M]; requires M % 64 == 0
        __shared__ unsigned short Tt[64][64];
#pragma unroll
        for (int n = 0; n < 4; ++n)
#pragma unroll
            for (int reg = 0; reg < 4; ++reg)
                Tt[n * 16 + lr][wv * 16 + lg * 4 + reg] = f2bf(acc[n][reg] + bv[n]);
        __syncthreads();
        unsigned short* CT = (unsigned short*)Cv;
        const int t = threadIdx.x;
#pragma unroll
        for (int p = 0; p < 2; ++p) {
            int row = p * 32 + (t >> 3);
            int seg = (t & 7) * 8;
            *(short8v*)(CT + (size_t)(n0 + row) * M + blockIdx.x * 64 + seg) =
                *(const short8v*)&Tt[row][seg];
        }
    }
}

// ---------------- sentence-level graph attention (bf16 in, fp32 math) ----------------
__global__ __launch_bounds__(256) void sent_attn(
    const unsigned short* __restrict__ qs, const unsigned short* __restrict__ ksb,
    const unsigned short* __restrict__ vsb, const float* __restrict__ bias_s,
    const float* __restrict__ gab, float* __restrict__ attns,
    unsigned short* __restrict__ ctxs)
{
    const int wid = blockIdx.x * 4 + (threadIdx.x >> 6);
    const int lane = threadIdx.x & 63;
    const int q = wid & (LQ - 1);
    const int bh = wid >> 8;
    const int h = bh & 7;
    const int b = bh >> 3;

    float qv = bf2f(qs[(size_t)(b * LQ + q) * 512 + h * 64 + lane]) * 0.125f;

    float sc = 0.f;
#pragma unroll
    for (int ss = 0; ss < NS; ++ss) {
        float r = qv * bf2f(ksb[(size_t)(b * NS + ss) * 512 + h * 64 + lane]);
#pragma unroll
        for (int off = 32; off; off >>= 1) r += __shfl_xor(r, off);
        if (lane == ss) sc = r;
    }
    float val = (lane < NS)
        ? sc + bias_s[((size_t)(b * HH + h) * LQ + q) * NS + lane]
        : -1e30f;

    float m = val;
#pragma unroll
    for (int off = 32; off; off >>= 1) m = fmaxf(m, __shfl_xor(m, off));
    float p = __expf(val - m);
    float sum = p;
#pragma unroll
    for (int off = 32; off; off >>= 1) sum += __shfl_xor(sum, off);
    p /= sum;

    const int tcl = (lane < NS) ? lane : (NS - 1);
    const float* gb = gab + (size_t)(b * HH + h) * NS * NS;
    float g = 0.f;
#pragma unroll
    for (int ss = 0; ss < NS; ++ss) {
        float ps = __shfl(p, ss);
        g += ps * gb[ss * NS + tcl];
    }
    float val2 = val - 0.5f * g * g;

    float m2 = val2;
#pragma unroll
    for (int off = 32; off; off >>= 1) m2 = fmaxf(m2, __shfl_xor(m2, off));
    float a = __expf(val2 - m2);
    float sum2 = a;
#pragma unroll
    for (int off = 32; off; off >>= 1) sum2 += __shfl_xor(sum2, off);
    a /= sum2;

    if (lane < NS)
        attns[((size_t)(b * HH + h) * LQ + q) * NS + lane] = a;

    float ctx = 0.f;
#pragma unroll
    for (int ss = 0; ss < NS; ++ss) {
        float as = __shfl(a, ss);
        ctx += as * bf2f(vsb[(size_t)(b * NS + ss) * 512 + h * 64 + lane]);
    }
    ctxs[(size_t)(b * LQ + q) * 512 + h * 64 + lane] = f2bf(ctx);
}

// ---------------- word-level attention via MFMA, 8 s-partials ----------------
// grid 1024: bid -> sp(0..7), qt(0..3), h(0..7), b(0..3). 4 waves, wave = 16 q rows.
__global__ __launch_bounds__(256) void word_attn_mfma(
    const unsigned short* __restrict__ qwb,   // [B*LQ, 512] bf16
    const unsigned short* __restrict__ kwb,   // [B*NS*NT, 512] bf16
    const unsigned short* __restrict__ vwbT,  // [512, B*NS*NT] bf16 (transposed)
    const float* __restrict__ bias_w,         // [B,NS,H,LQ,NT] fp32
    const float* __restrict__ attns,          // [B,H,LQ,NS] fp32
    float* __restrict__ part)                 // [8][B][H][LQ][64] fp32
{
    __shared__ __align__(16) unsigned short P_lds[4][16][136];
    const int bid = blockIdx.x;
    const int sp = bid & 7;
    const int qt = (bid >> 3) & 3;
    const int h  = (bid >> 5) & 7;
    const int b  = bid >> 8;
    const int tid = threadIdx.x;
    const int wv = tid >> 6;
    const int l  = tid & 63;
    const int lr = l & 15;
    const int lg = l >> 4;
    const int q0 = qt * 64 + wv * 16;
    const int MW = BB * NS * NT;   // 12288

    const unsigned short* qbase = qwb + (size_t)(b * LQ + q0 + lr) * 512 + h * 64 + lg * 8;
    short8v aq0 = *(const short8v*)(qbase);
    short8v aq1 = *(const short8v*)(qbase + 32);

    f32x4 out0 = {0.f,0.f,0.f,0.f}, out1 = out0, out2 = out0, out3 = out0;

    for (int si = 0; si < 3; ++si) {
        const int s = sp * 3 + si;
        // ---- scores: S[16q x 128t] = Q @ K^T ----
        f32x4 sc[8];
        const unsigned short* kbase = kwb + (size_t)((b * NS + s) * NT + lr) * 512 + h * 64 + lg * 8;
#pragma unroll
        for (int n = 0; n < 8; ++n) {
            const unsigned short* kp = kbase + (size_t)n * 16 * 512;
            short8v bk0 = *(const short8v*)(kp);
            short8v bk1 = *(const short8v*)(kp + 32);
            f32x4 z = {0.f,0.f,0.f,0.f};
            z = __builtin_amdgcn_mfma_f32_16x16x32_bf16(aq0, bk0, z, 0, 0, 0);
            sc[n] = __builtin_amdgcn_mfma_f32_16x16x32_bf16(aq1, bk1, z, 0, 0, 0);
        }
        // ---- bias + softmax + attns renorm (rows q = q0 + lg*4 + reg) ----
        const float* bb = bias_w + ((((size_t)(b * NS + s) * HH + h) * LQ) + q0 + lg * 4) * NT + lr;
#pragma unroll
        for (int reg = 0; reg < 4; ++reg) {
            float v0 = sc[0][reg] * 0.125f + bb[(size_t)reg * NT +   0];
            float v1 = sc[1][reg] * 0.125f + bb[(size_t)reg * NT +  16];
            float v2 = sc[2][reg] * 0.125f + bb[(size_t)reg * NT +  32];
            float v3 = sc[3][reg] * 0.125f + bb[(size_t)reg * NT +  48];
            float v4 = sc[4][reg] * 0.125f + bb[(size_t)reg * NT +  64];
            float v5 = sc[5][reg] * 0.125f + bb[(size_t)reg * NT +  80];
            float v6 = sc[6][reg] * 0.125f + bb[(size_t)reg * NT +  96];
            float v7 = sc[7][reg] * 0.125f + bb[(size_t)reg * NT + 112];
            float mx = fmaxf(fmaxf(fmaxf(v0, v1), fmaxf(v2, v3)),
                             fmaxf(fmaxf(v4, v5), fmaxf(v6, v7)));
            mx = fmaxf(mx, __shfl_xor(mx, 1));
            mx = fmaxf(mx, __shfl_xor(mx, 2));
            mx = fmaxf(mx, __shfl_xor(mx, 4));
            mx = fmaxf(mx, __shfl_xor(mx, 8));
            v0 = __expf(v0 - mx); v1 = __expf(v1 - mx); v2 = __expf(v2 - mx); v3 = __expf(v3 - mx);
            v4 = __expf(v4 - mx); v5 = __expf(v5 - mx); v6 = __expf(v6 - mx); v7 = __expf(v7 - mx);
            float sm = ((v0 + v1) + (v2 + v3)) + ((v4 + v5) + (v6 + v7));
            sm += __shfl_xor(sm, 1);
            sm += __shfl_xor(sm, 2);
            sm += __shfl_xor(sm, 4);
            sm += __shfl_xor(sm, 8);
            float at = attns[((size_t)(b * HH + h) * LQ + q0 + lg * 4 + reg) * NS + s];
            float fac = at / sm;
            const int qrow = lg * 4 + reg;
            P_lds[wv][qrow][  0 + lr] = f2bf(v0 * fac);
            P_lds[wv][qrow][ 16 + lr] = f2bf(v1 * fac);
            P_lds[wv][qrow][ 32 + lr] = f2bf(v2 * fac);
            P_lds[wv][qrow][ 48 + lr] = f2bf(v3 * fac);
            P_lds[wv][qrow][ 64 + lr] = f2bf(v4 * fac);
            P_lds[wv][qrow][ 80 + lr] = f2bf(v5 * fac);
            P_lds[wv][qrow][ 96 + lr] = f2bf(v6 * fac);
            P_lds[wv][qrow][112 + lr] = f2bf(v7 * fac);
        }
        // ---- PV: out[16q x 64d] += P @ V ----
        const unsigned short* vb = vwbT + (size_t)(h * 64 + lr) * MW + (size_t)(b * NS + s) * NT + lg * 8;
#pragma unroll
        for (int ks = 0; ks < 4; ++ks) {
            short8v pa = *(const short8v*)&P_lds[wv][lr][ks * 32 + lg * 8];
            const unsigned short* vk = vb + ks * 32;
            short8v bv0 = *(const short8v*)(vk);
            short8v bv1 = *(const short8v*)(vk + (size_t)16 * MW);
            short8v bv2 = *(const short8v*)(vk + (size_t)32 * MW);
            short8v bv3 = *(const short8v*)(vk + (size_t)48 * MW);
            out0 = __builtin_amdgcn_mfma_f32_16x16x32_bf16(pa, bv0, out0, 0, 0, 0);
            out1 = __builtin_amdgcn_mfma_f32_16x16x32_bf16(pa, bv1, out1, 0, 0, 0);
            out2 = __builtin_amdgcn_mfma_f32_16x16x32_bf16(pa, bv2, out2, 0, 0, 0);
            out3 = __builtin_amdgcn_mfma_f32_16x16x32_bf16(pa, bv3, out3, 0, 0, 0);
        }
    }
    float* pp = part + ((((size_t)sp * BB + b) * HH + h) * LQ) * 64;
#pragma unroll
    for (int reg = 0; reg < 4; ++reg) {
        const size_t ro = (size_t)(q0 + lg * 4 + reg) * 64 + lr;
        pp[ro +  0] = out0[reg];
        pp[ro + 16] = out1[reg];
        pp[ro + 32] = out2[reg];
        pp[ro + 48] = out3[reg];
    }
}

// ---------------- reduce 8 s-partials -> ctxw bf16 [B,LQ,512] ----------------
__global__ __launch_bounds__(256) void reduce_part(
    const float* __restrict__ part, unsigned short* __restrict__ ctxw)
{
    int idx = blockIdx.x * 256 + threadIdx.x;   // 524288
    int d = idx & 63;
    int q = (idx >> 6) & 255;
    int h = (idx >> 14) & 7;
    int b = idx >> 17;
    size_t o = ((((size_t)b * HH + h) * LQ) + q) * 64 + d;
    const size_t stride = (size_t)BB * HH * LQ * 64;
    float acc = 0.f;
#pragma unroll
    for (int sp = 0; sp < 8; ++sp) acc += part[o + sp * stride];
    ctxw[((size_t)(b * LQ + q)) * 512 + h * 64 + d] = f2bf(acc);
}

extern "C" void kernel_launch(void* const* d_in, const int* in_sizes, int n_in,
                              void* d_out, int out_size, void* d_ws, size_t ws_size,
                              hipStream_t stream) {
    const float* q_in   = (const float*)d_in[0];
    const float* k_s    = (const float*)d_in[1];
    const float* v_s    = (const float*)d_in[2];
    const float* k_w    = (const float*)d_in[3];
    const float* v_w    = (const float*)d_in[4];
    const float* bias_w = (const float*)d_in[5];
    const float* bias_s = (const float*)d_in[6];
    const float* gab    = (const float*)d_in[7];
    const float* wq_s = (const float*)d_in[8];
    const float* wk_s = (const float*)d_in[9];
    const float* wv_s = (const float*)d_in[10];
    const float* wq_w = (const float*)d_in[11];
    const float* wk_w = (const float*)d_in[12];
    const float* wv_w = (const float*)d_in[13];
    const float* fcs_w = (const float*)d_in[14];
    const float* fcw_w = (const float*)d_in[15];
    const float* bq_s = (const float*)d_in[16];
    const float* bk_s = (const float*)d_in[17];
    const float* bv_s = (const float*)d_in[18];
    const float* bq_w = (const float*)d_in[19];
    const float* bk_w = (const float*)d_in[20];
    const float* bv_w = (const float*)d_in[21];
    const float* fcs_b = (const float*)d_in[22];
    const float* fcw_b = (const float*)d_in[23];
    const float* fco_w = (const float*)d_in[24];
    const float* fco_b = (const float*)d_in[25];
    float* out = (float*)d_out;

    // ---- workspace layout ----
    float* attns = (float*)d_ws;                               // 196608 f32
    unsigned short* base = (unsigned short*)(attns + 196608);
    unsigned short* ctxs  = base;                              // 524288
    unsigned short* ctxw  = ctxs  + 524288;                    // 524288
    unsigned short* qb    = ctxw  + 524288;                    // 524288 } cat aliases
    unsigned short* qs_b  = qb    + 524288;                    // 524288 }
    unsigned short* ks_in = qs_b  + 524288;                    // 49152
    unsigned short* vs_in = ks_in + 49152;                     // 49152
    unsigned short* ksp   = vs_in + 49152;                     // 49152
    unsigned short* vsp   = ksp   + 49152;                     // 49152
    unsigned short* qwb   = vsp   + 49152;                     // 524288
    unsigned short* kwb   = qwb   + 524288;                    // 6291456
    unsigned short* vwbT  = kwb   + 6291456;                   // 6291456
    unsigned short* kw_in = vwbT  + 6291456;                   // 6291456 } part aliases
    unsigned short* vw_in = kw_in + 6291456;                   // 6291456 }
    unsigned short* wts   = vw_in + 6291456;                   // 2621440 (9 transposed weights)
    float* part = (float*)kw_in;   // 4194304 f32 (16.8 MB <= 25.2 MB; kw_in/vw_in dead after projections)
    unsigned short* cat = qb;      // 1048576 (qb/qs_b dead after sent_attn)
    // total ~59.1 MB

    WTArgs wa;
    const float* wsrc[9] = {wq_s, wk_s, wv_s, wq_w, wk_w, wv_w, fcs_w, fcw_w, fco_w};
    for (int i = 0; i < 9; ++i) {
        wa.w[i]  = wsrc[i];
        wa.wt[i] = wts + (size_t)i * 262144;
        wa.K[i]  = (i == 8) ? 1024 : 512;
    }
    unsigned short* wtq_s = wts;
    unsigned short* wtk_s = wts + 262144;
    unsigned short* wtv_s = wts + 2 * 262144;
    unsigned short* wtq_w = wts + 3 * 262144;
    unsigned short* wtk_w = wts + 4 * 262144;
    unsigned short* wtv_w = wts + 5 * 262144;
    unsigned short* wtfcs = wts + 6 * 262144;
    unsigned short* wtfcw = wts + 7 * 262144;
    unsigned short* wtfco = wts + 8 * 262144;

    dim3 blk(256);
    // input casts + weight transposes
    cast5<<<6448, blk, 0, stream>>>(q_in, k_s, v_s, k_w, v_w, qb, ks_in, vs_in, kw_in, vw_in);
    wtrans<<<dim3(16, 8, 9), blk, 0, stream>>>(wa);
    // projections (bf16 MFMA)
    gemm_mfma<1, 512><<<dim3(16, 8),  blk, 0, stream>>>(qb,    wtq_s, bq_s, qs_b, 1024,  512, 0);
    gemm_mfma<1, 512><<<dim3(2, 8),   blk, 0, stream>>>(ks_in, wtk_s, bk_s, ksp,  96,    512, 0);
    gemm_mfma<1, 512><<<dim3(2, 8),   blk, 0, stream>>>(vs_in, wtv_s, bv_s, vsp,  96,    512, 0);
    gemm_mfma<1, 512><<<dim3(16, 8),  blk, 0, stream>>>(qb,    wtq_w, bq_w, qwb,  1024,  512, 0);
    gemm_mfma<1, 512><<<dim3(192, 8), blk, 0, stream>>>(kw_in, wtk_w, bk_w, kwb,  12288, 512, 0);
    gemm_mfma<2, 512><<<dim3(192, 8), blk, 0, stream>>>(vw_in, wtv_w, bv_w, vwbT, 12288, 0,   0);
    // sentence attention
    sent_attn<<<2048, blk, 0, stream>>>(qs_b, ksp, vsp, bias_s, gab, attns, ctxs);
    // word attention (MFMA, 8 partials) + reduce
    word_attn_mfma<<<1024, blk, 0, stream>>>(qwb, kwb, vwbT, bias_w, attns, part);
    reduce_part<<<2048, blk, 0, stream>>>(part, ctxw);
    // output projections
    gemm_mfma<1, 512> <<<dim3(16, 8), blk, 0, stream>>>(ctxs, wtfcs, fcs_b, cat, 1024, 1024, 0);
    gemm_mfma<1, 512> <<<dim3(16, 8), blk, 0, stream>>>(ctxw, wtfcw, fcw_b, cat, 1024, 1024, 512);
    gemm_mfma<0, 1024><<<dim3(16, 8), blk, 0, stream>>>(cat,  wtfco, fco_b, out, 1024, 512,  0);
}

// Round 5
// 430.645 us; speedup vs baseline: 3.8650x; 1.2154x over previous
//
#include <hip/hip_runtime.h>
#include <hip/hip_bf16.h>
#include <cstddef>

#define BB 4
#define LQ 256
#define NS 24
#define NT 128
#define DD 512
#define HH 8
#define DKK 64
// scale = DK^-0.5 = 0.125

typedef short short8v __attribute__((ext_vector_type(8)));   // 8 bf16 in 4 VGPRs
typedef float f32x4 __attribute__((ext_vector_type(4)));

__device__ __forceinline__ unsigned short f2bf(float f) {
    unsigned u = __float_as_uint(f);
    return (unsigned short)((u + 0x7fffu + ((u >> 16) & 1u)) >> 16);
}
__device__ __forceinline__ float bf2f(unsigned short u) {
    return __uint_as_float(((unsigned)u) << 16);
}
__device__ __forceinline__ void gload_lds16(const unsigned short* g, unsigned short* l) {
    __builtin_amdgcn_global_load_lds(
        (const __attribute__((address_space(1))) void*)g,
        (__attribute__((address_space(3))) void*)l, 16, 0, 0);
}

// ---------------- fused input casts: q, k_s, v_s, k_w, v_w -> bf16 ----------------
__global__ __launch_bounds__(256) void cast5(
    const float* __restrict__ q, const float* __restrict__ ks, const float* __restrict__ vs,
    const float* __restrict__ kw, const float* __restrict__ vw,
    unsigned short* __restrict__ qb, unsigned short* __restrict__ ksb,
    unsigned short* __restrict__ vsb, unsigned short* __restrict__ kwb,
    unsigned short* __restrict__ vwb)
{
    int t = blockIdx.x * 256 + threadIdx.x;   // each thread: 8 elements
    const float* src; unsigned short* dst; size_t i;
    if (t < 65536)        { src = q;  dst = qb;  i = (size_t)t * 8; }
    else if (t < 71680)   { src = ks; dst = ksb; i = (size_t)(t - 65536) * 8; }
    else if (t < 77824)   { src = vs; dst = vsb; i = (size_t)(t - 71680) * 8; }
    else if (t < 864256)  { src = kw; dst = kwb; i = (size_t)(t - 77824) * 8; }
    else                  { src = vw; dst = vwb; i = (size_t)(t - 864256) * 8; }
    float4 a = *(const float4*)(src + i);
    float4 b = *(const float4*)(src + i + 4);
    short8v o;
    o[0] = f2bf(a.x); o[1] = f2bf(a.y); o[2] = f2bf(a.z); o[3] = f2bf(a.w);
    o[4] = f2bf(b.x); o[5] = f2bf(b.y); o[6] = f2bf(b.z); o[7] = f2bf(b.w);
    *(short8v*)(dst + i) = o;
}

// ---------------- weight transpose-cast: WT[n][k] = bf16(W[k][n]), N=512 ----------------
struct WTArgs {
    const float* w[9];
    unsigned short* wt[9];
    int K[9];
};
__global__ __launch_bounds__(256) void wtrans(WTArgs a) {
    const int widx = blockIdx.z;
    const int K = a.K[widx];
    const int kt = blockIdx.x;
    if (kt * 64 >= K) return;
    const int nt = blockIdx.y;
    const float* W = a.w[widx];
    unsigned short* WT = a.wt[widx];
    __shared__ float T[64][65];
    const int tx = threadIdx.x & 63, ty = threadIdx.x >> 6;
    const int k0 = kt * 64, n0 = nt * 64;
#pragma unroll
    for (int r = 0; r < 16; ++r)
        T[ty * 16 + r][tx] = W[(size_t)(k0 + ty * 16 + r) * 512 + n0 + tx];
    __syncthreads();
#pragma unroll
    for (int r = 0; r < 16; ++r)
        WT[(size_t)(n0 + ty * 16 + r) * K + k0 + tx] = f2bf(T[tx][ty * 16 + r]);
}

// ---------------- LDS-staged MFMA GEMM: C[M,N=512] = A_bf16[M,K] @ WT_bf16[N,K]^T + bias ----
// 128x128 tile, BK=32, 4 waves (2x2), wave = 64x64. global_load_lds width-16.
// LDS chunk swizzle: LDS(r, c) holds global 8-elem k-chunk (c ^ ((r>>1)&3)) of row r.
// MODE 0: f32 out; MODE 1: bf16 out; MODE 2: bf16 transposed out CT[N][M] (M%128==0).
template<int MODE, int K>
__global__ __launch_bounds__(256) void gemm_mfma(
    const unsigned short* __restrict__ A, const unsigned short* __restrict__ WT,
    const float* __restrict__ bias, void* __restrict__ Cv, int M, int ldc, int coloff)
{
    __shared__ __align__(16) unsigned short Alds[128 * 32];
    __shared__ __align__(16) unsigned short Blds[128 * 32];
    __shared__ __align__(16) unsigned short Tt[(MODE == 2) ? 128 * 138 : 64];
    const int tid = threadIdx.x;
    const int wv = tid >> 6, l = tid & 63;
    const int lr = l & 15, lg = l >> 4;
    const int wr = wv >> 1, wc = wv & 1;
    const int bm = blockIdx.x * 128, bn = blockIdx.y * 128;

    // staging coords for this lane: rows wv*32 + j*16 + l/4, chunk l&3 (inverse-swizzled source)
    const int srl = l >> 2;      // 0..15
    const int sc  = l & 3;       // dest chunk
    f32x4 acc[4][4];
#pragma unroll
    for (int i = 0; i < 4; ++i)
#pragma unroll
        for (int j = 0; j < 4; ++j) acc[i][j] = (f32x4){0.f, 0.f, 0.f, 0.f};

    for (int k0 = 0; k0 < K; k0 += 32) {
#pragma unroll
        for (int j = 0; j < 2; ++j) {
            const int r = wv * 32 + j * 16 + srl;
            const int cs = sc ^ ((r >> 1) & 3);
            int ra = bm + r; if (ra >= M) ra = M - 1;
            gload_lds16(A + (size_t)ra * K + k0 + cs * 8, Alds + (wv * 32 + j * 16) * 32);
            gload_lds16(WT + (size_t)(bn + r) * K + k0 + cs * 8, Blds + (wv * 32 + j * 16) * 32);
        }
        __syncthreads();
        short8v af[4], bf[4];
#pragma unroll
        for (int mf = 0; mf < 4; ++mf) {
            const int row = wr * 64 + mf * 16 + lr;
            af[mf] = *(const short8v*)(Alds + row * 32 + (lg ^ ((row >> 1) & 3)) * 8);
        }
#pragma unroll
        for (int nf = 0; nf < 4; ++nf) {
            const int row = wc * 64 + nf * 16 + lr;
            bf[nf] = *(const short8v*)(Blds + row * 32 + (lg ^ ((row >> 1) & 3)) * 8);
        }
#pragma unroll
        for (int mf = 0; mf < 4; ++mf)
#pragma unroll
            for (int nf = 0; nf < 4; ++nf)
                acc[mf][nf] = __builtin_amdgcn_mfma_f32_16x16x32_bf16(af[mf], bf[nf], acc[mf][nf], 0, 0, 0);
        __syncthreads();
    }

    float bv[4];
#pragma unroll
    for (int nf = 0; nf < 4; ++nf) bv[nf] = bias[bn + wc * 64 + nf * 16 + lr];

    if constexpr (MODE == 0) {
        float* C = (float*)Cv;
#pragma unroll
        for (int mf = 0; mf < 4; ++mf)
#pragma unroll
            for (int reg = 0; reg < 4; ++reg) {
                const int row = bm + wr * 64 + mf * 16 + lg * 4 + reg;
                if (row < M) {
#pragma unroll
                    for (int nf = 0; nf < 4; ++nf)
                        C[(size_t)row * ldc + coloff + bn + wc * 64 + nf * 16 + lr] = acc[mf][nf][reg] + bv[nf];
                }
            }
    } else if constexpr (MODE == 1) {
        unsigned short* C = (unsigned short*)Cv;
#pragma unroll
        for (int mf = 0; mf < 4; ++mf)
#pragma unroll
            for (int reg = 0; reg < 4; ++reg) {
                const int row = bm + wr * 64 + mf * 16 + lg * 4 + reg;
                if (row < M) {
#pragma unroll
                    for (int nf = 0; nf < 4; ++nf)
                        C[(size_t)row * ldc + coloff + bn + wc * 64 + nf * 16 + lr] = f2bf(acc[mf][nf][reg] + bv[nf]);
                }
            }
    } else {
        // transposed bf16 out CT[N][M]
#pragma unroll
        for (int nf = 0; nf < 4; ++nf)
#pragma unroll
            for (int mf = 0; mf < 4; ++mf)
#pragma unroll
                for (int reg = 0; reg < 4; ++reg)
                    Tt[(size_t)(wc * 64 + nf * 16 + lr) * 138 + wr * 64 + mf * 16 + lg * 4 + reg] =
                        f2bf(acc[mf][nf][reg] + bv[nf]);
        __syncthreads();
        unsigned short* CT = (unsigned short*)Cv;
        const int n = tid >> 1;
        const int half = tid & 1;
#pragma unroll
        for (int i = 0; i < 8; ++i) {
            const int m = half * 64 + i * 8;
            *(short8v*)(CT + (size_t)(bn + n) * M + bm + m) = *(const short8v*)(Tt + (size_t)n * 138 + m);
        }
    }
}

// ---------------- sentence-level graph attention (bf16 in, fp32 math) ----------------
__global__ __launch_bounds__(256) void sent_attn(
    const unsigned short* __restrict__ qs, const unsigned short* __restrict__ ksb,
    const unsigned short* __restrict__ vsb, const float* __restrict__ bias_s,
    const float* __restrict__ gab, float* __restrict__ attns,
    unsigned short* __restrict__ ctxs)
{
    const int wid = blockIdx.x * 4 + (threadIdx.x >> 6);
    const int lane = threadIdx.x & 63;
    const int q = wid & (LQ - 1);
    const int bh = wid >> 8;
    const int h = bh & 7;
    const int b = bh >> 3;

    float qv = bf2f(qs[(size_t)(b * LQ + q) * 512 + h * 64 + lane]) * 0.125f;

    float sc = 0.f;
#pragma unroll
    for (int ss = 0; ss < NS; ++ss) {
        float r = qv * bf2f(ksb[(size_t)(b * NS + ss) * 512 + h * 64 + lane]);
#pragma unroll
        for (int off = 32; off; off >>= 1) r += __shfl_xor(r, off);
        if (lane == ss) sc = r;
    }
    float val = (lane < NS)
        ? sc + bias_s[((size_t)(b * HH + h) * LQ + q) * NS + lane]
        : -1e30f;

    float m = val;
#pragma unroll
    for (int off = 32; off; off >>= 1) m = fmaxf(m, __shfl_xor(m, off));
    float p = __expf(val - m);
    float sum = p;
#pragma unroll
    for (int off = 32; off; off >>= 1) sum += __shfl_xor(sum, off);
    p /= sum;

    const int tcl = (lane < NS) ? lane : (NS - 1);
    const float* gb = gab + (size_t)(b * HH + h) * NS * NS;
    float g = 0.f;
#pragma unroll
    for (int ss = 0; ss < NS; ++ss) {
        float ps = __shfl(p, ss);
        g += ps * gb[ss * NS + tcl];
    }
    float val2 = val - 0.5f * g * g;

    float m2 = val2;
#pragma unroll
    for (int off = 32; off; off >>= 1) m2 = fmaxf(m2, __shfl_xor(m2, off));
    float a = __expf(val2 - m2);
    float sum2 = a;
#pragma unroll
    for (int off = 32; off; off >>= 1) sum2 += __shfl_xor(sum2, off);
    a /= sum2;

    if (lane < NS)
        attns[((size_t)(b * HH + h) * LQ + q) * NS + lane] = a;

    float ctx = 0.f;
#pragma unroll
    for (int ss = 0; ss < NS; ++ss) {
        float as = __shfl(a, ss);
        ctx += as * bf2f(vsb[(size_t)(b * NS + ss) * 512 + h * 64 + lane]);
    }
    ctxs[(size_t)(b * LQ + q) * 512 + h * 64 + lane] = f2bf(ctx);
}

// ---------------- word-level attention via MFMA, 24 s-partials (one s per block) --------
// grid 3072: bid -> sp(0..23) | qt(2) | h(3) | b(2). 4 waves, wave = 16 q rows.
__global__ __launch_bounds__(256) void word_attn_mfma(
    const unsigned short* __restrict__ qwb,   // [B*LQ, 512] bf16
    const unsigned short* __restrict__ kwb,   // [B*NS*NT, 512] bf16
    const unsigned short* __restrict__ vwbT,  // [512, B*NS*NT] bf16 (transposed)
    const float* __restrict__ bias_w,         // [B,NS,H,LQ,NT] fp32
    const float* __restrict__ attns,          // [B,H,LQ,NS] fp32
    unsigned short* __restrict__ part)        // [24][B][H][LQ][64] bf16
{
    __shared__ __align__(16) unsigned short P_lds[4][16][136];
    const int bid = blockIdx.x;
    const int s  = bid % 24;
    const int r_ = bid / 24;
    const int qt = r_ & 3;
    const int h  = (r_ >> 2) & 7;
    const int b  = r_ >> 5;
    const int tid = threadIdx.x;
    const int wv = tid >> 6;
    const int l  = tid & 63;
    const int lr = l & 15;
    const int lg = l >> 4;
    const int q0 = qt * 64 + wv * 16;
    const int MW = BB * NS * NT;   // 12288

    const unsigned short* qbase = qwb + (size_t)(b * LQ + q0 + lr) * 512 + h * 64 + lg * 8;
    short8v aq0 = *(const short8v*)(qbase);
    short8v aq1 = *(const short8v*)(qbase + 32);

    f32x4 out0 = {0.f,0.f,0.f,0.f}, out1 = out0, out2 = out0, out3 = out0;

    // ---- scores: S[16q x 128t] = Q @ K^T ----
    f32x4 sc[8];
    const unsigned short* kbase = kwb + (size_t)((b * NS + s) * NT + lr) * 512 + h * 64 + lg * 8;
#pragma unroll
    for (int n = 0; n < 8; ++n) {
        const unsigned short* kp = kbase + (size_t)n * 16 * 512;
        short8v bk0 = *(const short8v*)(kp);
        short8v bk1 = *(const short8v*)(kp + 32);
        f32x4 z = {0.f,0.f,0.f,0.f};
        z = __builtin_amdgcn_mfma_f32_16x16x32_bf16(aq0, bk0, z, 0, 0, 0);
        sc[n] = __builtin_amdgcn_mfma_f32_16x16x32_bf16(aq1, bk1, z, 0, 0, 0);
    }
    // ---- bias + softmax + attns renorm (rows q = q0 + lg*4 + reg) ----
    const float* bb = bias_w + ((((size_t)(b * NS + s) * HH + h) * LQ) + q0 + lg * 4) * NT + lr;
#pragma unroll
    for (int reg = 0; reg < 4; ++reg) {
        float v0 = sc[0][reg] * 0.125f + bb[(size_t)reg * NT +   0];
        float v1 = sc[1][reg] * 0.125f + bb[(size_t)reg * NT +  16];
        float v2 = sc[2][reg] * 0.125f + bb[(size_t)reg * NT +  32];
        float v3 = sc[3][reg] * 0.125f + bb[(size_t)reg * NT +  48];
        float v4 = sc[4][reg] * 0.125f + bb[(size_t)reg * NT +  64];
        float v5 = sc[5][reg] * 0.125f + bb[(size_t)reg * NT +  80];
        float v6 = sc[6][reg] * 0.125f + bb[(size_t)reg * NT +  96];
        float v7 = sc[7][reg] * 0.125f + bb[(size_t)reg * NT + 112];
        float mx = fmaxf(fmaxf(fmaxf(v0, v1), fmaxf(v2, v3)),
                         fmaxf(fmaxf(v4, v5), fmaxf(v6, v7)));
        mx = fmaxf(mx, __shfl_xor(mx, 1));
        mx = fmaxf(mx, __shfl_xor(mx, 2));
        mx = fmaxf(mx, __shfl_xor(mx, 4));
        mx = fmaxf(mx, __shfl_xor(mx, 8));
        v0 = __expf(v0 - mx); v1 = __expf(v1 - mx); v2 = __expf(v2 - mx); v3 = __expf(v3 - mx);
        v4 = __expf(v4 - mx); v5 = __expf(v5 - mx); v6 = __expf(v6 - mx); v7 = __expf(v7 - mx);
        float sm = ((v0 + v1) + (v2 + v3)) + ((v4 + v5) + (v6 + v7));
        sm += __shfl_xor(sm, 1);
        sm += __shfl_xor(sm, 2);
        sm += __shfl_xor(sm, 4);
        sm += __shfl_xor(sm, 8);
        float at = attns[((size_t)(b * HH + h) * LQ + q0 + lg * 4 + reg) * NS + s];
        float fac = at / sm;
        const int qrow = lg * 4 + reg;
        P_lds[wv][qrow][  0 + lr] = f2bf(v0 * fac);
        P_lds[wv][qrow][ 16 + lr] = f2bf(v1 * fac);
        P_lds[wv][qrow][ 32 + lr] = f2bf(v2 * fac);
        P_lds[wv][qrow][ 48 + lr] = f2bf(v3 * fac);
        P_lds[wv][qrow][ 64 + lr] = f2bf(v4 * fac);
        P_lds[wv][qrow][ 80 + lr] = f2bf(v5 * fac);
        P_lds[wv][qrow][ 96 + lr] = f2bf(v6 * fac);
        P_lds[wv][qrow][112 + lr] = f2bf(v7 * fac);
    }
    // ---- PV: out[16q x 64d] = P @ V ----
    const unsigned short* vb = vwbT + (size_t)(h * 64 + lr) * MW + (size_t)(b * NS + s) * NT + lg * 8;
#pragma unroll
    for (int ks = 0; ks < 4; ++ks) {
        short8v pa = *(const short8v*)&P_lds[wv][lr][ks * 32 + lg * 8];
        const unsigned short* vk = vb + ks * 32;
        short8v bv0 = *(const short8v*)(vk);
        short8v bv1 = *(const short8v*)(vk + (size_t)16 * MW);
        short8v bv2 = *(const short8v*)(vk + (size_t)32 * MW);
        short8v bv3 = *(const short8v*)(vk + (size_t)48 * MW);
        out0 = __builtin_amdgcn_mfma_f32_16x16x32_bf16(pa, bv0, out0, 0, 0, 0);
        out1 = __builtin_amdgcn_mfma_f32_16x16x32_bf16(pa, bv1, out1, 0, 0, 0);
        out2 = __builtin_amdgcn_mfma_f32_16x16x32_bf16(pa, bv2, out2, 0, 0, 0);
        out3 = __builtin_amdgcn_mfma_f32_16x16x32_bf16(pa, bv3, out3, 0, 0, 0);
    }
    unsigned short* pp = part + ((((size_t)s * BB + b) * HH + h) * LQ) * 64;
#pragma unroll
    for (int reg = 0; reg < 4; ++reg) {
        const size_t ro = (size_t)(q0 + lg * 4 + reg) * 64 + lr;
        pp[ro +  0] = f2bf(out0[reg]);
        pp[ro + 16] = f2bf(out1[reg]);
        pp[ro + 32] = f2bf(out2[reg]);
        pp[ro + 48] = f2bf(out3[reg]);
    }
}

// ---------------- reduce 24 bf16 s-partials -> ctxw bf16 [B,LQ,512] ----------------
__global__ __launch_bounds__(256) void reduce_part(
    const unsigned short* __restrict__ part, unsigned short* __restrict__ ctxw)
{
    int idx = blockIdx.x * 256 + threadIdx.x;   // 524288
    int d = idx & 63;
    int q = (idx >> 6) & 255;
    int h = (idx >> 14) & 7;
    int b = idx >> 17;
    size_t o = ((((size_t)b * HH + h) * LQ) + q) * 64 + d;
    const size_t stride = (size_t)BB * HH * LQ * 64;
    float acc = 0.f;
#pragma unroll
    for (int sp = 0; sp < 24; ++sp) acc += bf2f(part[o + sp * stride]);
    ctxw[((size_t)(b * LQ + q)) * 512 + h * 64 + d] = f2bf(acc);
}

extern "C" void kernel_launch(void* const* d_in, const int* in_sizes, int n_in,
                              void* d_out, int out_size, void* d_ws, size_t ws_size,
                              hipStream_t stream) {
    const float* q_in   = (const float*)d_in[0];
    const float* k_s    = (const float*)d_in[1];
    const float* v_s    = (const float*)d_in[2];
    const float* k_w    = (const float*)d_in[3];
    const float* v_w    = (const float*)d_in[4];
    const float* bias_w = (const float*)d_in[5];
    const float* bias_s = (const float*)d_in[6];
    const float* gab    = (const float*)d_in[7];
    const float* wq_s = (const float*)d_in[8];
    const float* wk_s = (const float*)d_in[9];
    const float* wv_s = (const float*)d_in[10];
    const float* wq_w = (const float*)d_in[11];
    const float* wk_w = (const float*)d_in[12];
    const float* wv_w = (const float*)d_in[13];
    const float* fcs_w = (const float*)d_in[14];
    const float* fcw_w = (const float*)d_in[15];
    const float* bq_s = (const float*)d_in[16];
    const float* bk_s = (const float*)d_in[17];
    const float* bv_s = (const float*)d_in[18];
    const float* bq_w = (const float*)d_in[19];
    const float* bk_w = (const float*)d_in[20];
    const float* bv_w = (const float*)d_in[21];
    const float* fcs_b = (const float*)d_in[22];
    const float* fcw_b = (const float*)d_in[23];
    const float* fco_w = (const float*)d_in[24];
    const float* fco_b = (const float*)d_in[25];
    float* out = (float*)d_out;

    // ---- workspace layout ----
    float* attns = (float*)d_ws;                               // 196608 f32
    unsigned short* base = (unsigned short*)(attns + 196608);
    unsigned short* ctxs  = base;                              // 524288
    unsigned short* ctxw  = ctxs  + 524288;                    // 524288
    unsigned short* qb    = ctxw  + 524288;                    // 524288 } cat aliases
    unsigned short* qs_b  = qb    + 524288;                    // 524288 }
    unsigned short* ks_in = qs_b  + 524288;                    // 49152
    unsigned short* vs_in = ks_in + 49152;                     // 49152
    unsigned short* ksp   = vs_in + 49152;                     // 49152
    unsigned short* vsp   = ksp   + 49152;                     // 49152
    unsigned short* qwb   = vsp   + 49152;                     // 524288
    unsigned short* kwb   = qwb   + 524288;                    // 6291456
    unsigned short* vwbT  = kwb   + 6291456;                   // 6291456
    unsigned short* kw_in = vwbT  + 6291456;                   // 6291456 } part aliases (24 bf16 partials = exactly kw_in+vw_in)
    unsigned short* vw_in = kw_in + 6291456;                   // 6291456 }
    unsigned short* wts   = vw_in + 6291456;                   // 2621440 (9 transposed weights)
    unsigned short* part = kw_in;  // [24][B][H][LQ][64] bf16 = 12,582,912 shorts (kw_in/vw_in dead after projections)
    unsigned short* cat = qb;      // 1048576 (qb/qs_b dead after sent_attn)
    // total ~62 MB

    WTArgs wa;
    const float* wsrc[9] = {wq_s, wk_s, wv_s, wq_w, wk_w, wv_w, fcs_w, fcw_w, fco_w};
    for (int i = 0; i < 9; ++i) {
        wa.w[i]  = wsrc[i];
        wa.wt[i] = wts + (size_t)i * 262144;
        wa.K[i]  = (i == 8) ? 1024 : 512;
    }
    unsigned short* wtq_s = wts;
    unsigned short* wtk_s = wts + 262144;
    unsigned short* wtv_s = wts + 2 * 262144;
    unsigned short* wtq_w = wts + 3 * 262144;
    unsigned short* wtk_w = wts + 4 * 262144;
    unsigned short* wtv_w = wts + 5 * 262144;
    unsigned short* wtfcs = wts + 6 * 262144;
    unsigned short* wtfcw = wts + 7 * 262144;
    unsigned short* wtfco = wts + 8 * 262144;

    dim3 blk(256);
    // input casts + weight transposes
    cast5<<<6448, blk, 0, stream>>>(q_in, k_s, v_s, k_w, v_w, qb, ks_in, vs_in, kw_in, vw_in);
    wtrans<<<dim3(16, 8, 9), blk, 0, stream>>>(wa);
    // projections (bf16 MFMA, LDS-staged 128x128)
    gemm_mfma<1, 512><<<dim3(8, 4),  blk, 0, stream>>>(qb,    wtq_s, bq_s, qs_b, 1024,  512, 0);
    gemm_mfma<1, 512><<<dim3(1, 4),  blk, 0, stream>>>(ks_in, wtk_s, bk_s, ksp,  96,    512, 0);
    gemm_mfma<1, 512><<<dim3(1, 4),  blk, 0, stream>>>(vs_in, wtv_s, bv_s, vsp,  96,    512, 0);
    gemm_mfma<1, 512><<<dim3(8, 4),  blk, 0, stream>>>(qb,    wtq_w, bq_w, qwb,  1024,  512, 0);
    gemm_mfma<1, 512><<<dim3(96, 4), blk, 0, stream>>>(kw_in, wtk_w, bk_w, kwb,  12288, 512, 0);
    gemm_mfma<2, 512><<<dim3(96, 4), blk, 0, stream>>>(vw_in, wtv_w, bv_w, vwbT, 12288, 0,   0);
    // sentence attention
    sent_attn<<<2048, blk, 0, stream>>>(qs_b, ksp, vsp, bias_s, gab, attns, ctxs);
    // word attention (MFMA, 24 partials) + reduce
    word_attn_mfma<<<3072, blk, 0, stream>>>(qwb, kwb, vwbT, bias_w, attns, part);
    reduce_part<<<2048, blk, 0, stream>>>(part, ctxw);
    // output projections
    gemm_mfma<1, 512> <<<dim3(8, 4), blk, 0, stream>>>(ctxs, wtfcs, fcs_b, cat, 1024, 1024, 0);
    gemm_mfma<1, 512> <<<dim3(8, 4), blk, 0, stream>>>(ctxw, wtfcw, fcw_b, cat, 1024, 1024, 512);
    gemm_mfma<0, 1024><<<dim3(8, 4), blk, 0, stream>>>(cat,  wtfco, fco_b, out, 1024, 512,  0);
}

// Round 6
// 372.270 us; speedup vs baseline: 4.4711x; 1.1568x over previous
//
#include <hip/hip_runtime.h>
#include <hip/hip_bf16.h>
#include <cstddef>

#define BB 4
#define LQ 256
#define NS 24
#define NT 128
#define DD 512
#define HH 8
#define DKK 64
// scale = DK^-0.5 = 0.125

typedef short short8v __attribute__((ext_vector_type(8)));   // 8 bf16 in 4 VGPRs
typedef float f32x4 __attribute__((ext_vector_type(4)));

__device__ __forceinline__ unsigned short f2bf(float f) {
    unsigned u = __float_as_uint(f);
    return (unsigned short)((u + 0x7fffu + ((u >> 16) & 1u)) >> 16);
}
__device__ __forceinline__ float bf2f(unsigned short u) {
    return __uint_as_float(((unsigned)u) << 16);
}
__device__ __forceinline__ void gload_lds16(const void* g, void* l) {
    __builtin_amdgcn_global_load_lds(
        (const __attribute__((address_space(1))) void*)g,
        (__attribute__((address_space(3))) void*)l, 16, 0, 0);
}

// ---------------- fused input casts: q, k_s, v_s, k_w, v_w -> bf16 ----------------
__global__ __launch_bounds__(256) void cast5(
    const float* __restrict__ q, const float* __restrict__ ks, const float* __restrict__ vs,
    const float* __restrict__ kw, const float* __restrict__ vw,
    unsigned short* __restrict__ qb, unsigned short* __restrict__ ksb,
    unsigned short* __restrict__ vsb, unsigned short* __restrict__ kwb,
    unsigned short* __restrict__ vwb)
{
    int t = blockIdx.x * 256 + threadIdx.x;   // each thread: 8 elements
    const float* src; unsigned short* dst; size_t i;
    if (t < 65536)        { src = q;  dst = qb;  i = (size_t)t * 8; }
    else if (t < 71680)   { src = ks; dst = ksb; i = (size_t)(t - 65536) * 8; }
    else if (t < 77824)   { src = vs; dst = vsb; i = (size_t)(t - 71680) * 8; }
    else if (t < 864256)  { src = kw; dst = kwb; i = (size_t)(t - 77824) * 8; }
    else                  { src = vw; dst = vwb; i = (size_t)(t - 864256) * 8; }
    float4 a = *(const float4*)(src + i);
    float4 b = *(const float4*)(src + i + 4);
    short8v o;
    o[0] = f2bf(a.x); o[1] = f2bf(a.y); o[2] = f2bf(a.z); o[3] = f2bf(a.w);
    o[4] = f2bf(b.x); o[5] = f2bf(b.y); o[6] = f2bf(b.z); o[7] = f2bf(b.w);
    *(short8v*)(dst + i) = o;
}

// ---------------- weight transpose-cast: WT[n][k] = bf16(W[k][n]), N=512 ----------------
struct WTArgs {
    const float* w[9];
    unsigned short* wt[9];
    int K[9];
};
__global__ __launch_bounds__(256) void wtrans(WTArgs a) {
    const int widx = blockIdx.z;
    const int K = a.K[widx];
    const int kt = blockIdx.x;
    if (kt * 64 >= K) return;
    const int nt = blockIdx.y;
    const float* W = a.w[widx];
    unsigned short* WT = a.wt[widx];
    __shared__ float T[64][65];
    const int tx = threadIdx.x & 63, ty = threadIdx.x >> 6;
    const int k0 = kt * 64, n0 = nt * 64;
#pragma unroll
    for (int r = 0; r < 16; ++r)
        T[ty * 16 + r][tx] = W[(size_t)(k0 + ty * 16 + r) * 512 + n0 + tx];
    __syncthreads();
#pragma unroll
    for (int r = 0; r < 16; ++r)
        WT[(size_t)(n0 + ty * 16 + r) * K + k0 + tx] = f2bf(T[tx][ty * 16 + r]);
}

// ---------------- LDS-staged MFMA GEMM core (128x128 tile, BK=32, 4 waves) ----------------
// MODE 0: f32 out; MODE 1: bf16 out; MODE 2: bf16 transposed out CT[N][M] (M%128==0).
template<int MODE, int K>
__device__ __forceinline__ void gemm_core(
    const unsigned short* __restrict__ A, const unsigned short* __restrict__ WT,
    const float* __restrict__ bias, void* __restrict__ Cv, int M, int ldc, int coloff,
    int bx, int by)
{
    __shared__ __align__(16) unsigned short Alds[128 * 32];
    __shared__ __align__(16) unsigned short Blds[128 * 32];
    __shared__ __align__(16) unsigned short Tt[(MODE == 2) ? 128 * 138 : 64];
    const int tid = threadIdx.x;
    const int wv = tid >> 6, l = tid & 63;
    const int lr = l & 15, lg = l >> 4;
    const int wr = wv >> 1, wc = wv & 1;
    const int bm = bx * 128, bn = by * 128;

    const int srl = l >> 2;      // 0..15
    const int sc  = l & 3;       // dest chunk
    f32x4 acc[4][4];
#pragma unroll
    for (int i = 0; i < 4; ++i)
#pragma unroll
        for (int j = 0; j < 4; ++j) acc[i][j] = (f32x4){0.f, 0.f, 0.f, 0.f};

    for (int k0 = 0; k0 < K; k0 += 32) {
#pragma unroll
        for (int j = 0; j < 2; ++j) {
            const int r = wv * 32 + j * 16 + srl;
            const int cs = sc ^ ((r >> 1) & 3);
            int ra = bm + r; if (ra >= M) ra = M - 1;
            gload_lds16(A + (size_t)ra * K + k0 + cs * 8, Alds + (wv * 32 + j * 16) * 32);
            gload_lds16(WT + (size_t)(bn + r) * K + k0 + cs * 8, Blds + (wv * 32 + j * 16) * 32);
        }
        __syncthreads();
        short8v af[4], bf[4];
#pragma unroll
        for (int mf = 0; mf < 4; ++mf) {
            const int row = wr * 64 + mf * 16 + lr;
            af[mf] = *(const short8v*)(Alds + row * 32 + (lg ^ ((row >> 1) & 3)) * 8);
        }
#pragma unroll
        for (int nf = 0; nf < 4; ++nf) {
            const int row = wc * 64 + nf * 16 + lr;
            bf[nf] = *(const short8v*)(Blds + row * 32 + (lg ^ ((row >> 1) & 3)) * 8);
        }
#pragma unroll
        for (int mf = 0; mf < 4; ++mf)
#pragma unroll
            for (int nf = 0; nf < 4; ++nf)
                acc[mf][nf] = __builtin_amdgcn_mfma_f32_16x16x32_bf16(af[mf], bf[nf], acc[mf][nf], 0, 0, 0);
        __syncthreads();
    }

    float bv[4];
#pragma unroll
    for (int nf = 0; nf < 4; ++nf) bv[nf] = bias[bn + wc * 64 + nf * 16 + lr];

    if constexpr (MODE == 0) {
        float* C = (float*)Cv;
#pragma unroll
        for (int mf = 0; mf < 4; ++mf)
#pragma unroll
            for (int reg = 0; reg < 4; ++reg) {
                const int row = bm + wr * 64 + mf * 16 + lg * 4 + reg;
                if (row < M) {
#pragma unroll
                    for (int nf = 0; nf < 4; ++nf)
                        C[(size_t)row * ldc + coloff + bn + wc * 64 + nf * 16 + lr] = acc[mf][nf][reg] + bv[nf];
                }
            }
    } else if constexpr (MODE == 1) {
        unsigned short* C = (unsigned short*)Cv;
#pragma unroll
        for (int mf = 0; mf < 4; ++mf)
#pragma unroll
            for (int reg = 0; reg < 4; ++reg) {
                const int row = bm + wr * 64 + mf * 16 + lg * 4 + reg;
                if (row < M) {
#pragma unroll
                    for (int nf = 0; nf < 4; ++nf)
                        C[(size_t)row * ldc + coloff + bn + wc * 64 + nf * 16 + lr] = f2bf(acc[mf][nf][reg] + bv[nf]);
                }
            }
    } else {
        // transposed bf16 out CT[N][M]
#pragma unroll
        for (int nf = 0; nf < 4; ++nf)
#pragma unroll
            for (int mf = 0; mf < 4; ++mf)
#pragma unroll
                for (int reg = 0; reg < 4; ++reg)
                    Tt[(size_t)(wc * 64 + nf * 16 + lr) * 138 + wr * 64 + mf * 16 + lg * 4 + reg] =
                        f2bf(acc[mf][nf][reg] + bv[nf]);
        __syncthreads();
        unsigned short* CT = (unsigned short*)Cv;
        const int n = tid >> 1;
        const int half = tid & 1;
#pragma unroll
        for (int i = 0; i < 8; ++i) {
            const int m = half * 64 + i * 8;
            *(short8v*)(CT + (size_t)(bn + n) * M + bm + m) = *(const short8v*)(Tt + (size_t)n * 138 + m);
        }
    }
}

template<int MODE, int K>
__global__ __launch_bounds__(256) void gemm_mfma(
    const unsigned short* __restrict__ A, const unsigned short* __restrict__ WT,
    const float* __restrict__ bias, void* __restrict__ Cv, int M, int ldc, int coloff)
{
    gemm_core<MODE, K>(A, WT, bias, Cv, M, ldc, coloff, blockIdx.x, blockIdx.y);
}

// ---------------- batched MODE1 K=512 GEMMs (z-dim selects problem) ----------------
struct GB {
    const unsigned short* A[5];
    const unsigned short* WT[5];
    const float* bias[5];
    unsigned short* C[5];
    int M[5];
    int ldc[5];
    int coloff[5];
};
__global__ __launch_bounds__(256) void gemm_batch(GB g) {
    const int z = blockIdx.z;
    const int M = g.M[z];
    if ((int)blockIdx.x * 128 >= M) return;
    gemm_core<1, 512>(g.A[z], g.WT[z], g.bias[z], g.C[z], M, g.ldc[z], g.coloff[z],
                      blockIdx.x, blockIdx.y);
}

// ---------------- sentence-level graph attention (bf16 in, fp32 math) ----------------
__global__ __launch_bounds__(256) void sent_attn(
    const unsigned short* __restrict__ qs, const unsigned short* __restrict__ ksb,
    const unsigned short* __restrict__ vsb, const float* __restrict__ bias_s,
    const float* __restrict__ gab, float* __restrict__ attns,
    unsigned short* __restrict__ ctxs)
{
    const int wid = blockIdx.x * 4 + (threadIdx.x >> 6);
    const int lane = threadIdx.x & 63;
    const int q = wid & (LQ - 1);
    const int bh = wid >> 8;
    const int h = bh & 7;
    const int b = bh >> 3;

    float qv = bf2f(qs[(size_t)(b * LQ + q) * 512 + h * 64 + lane]) * 0.125f;

    float sc = 0.f;
#pragma unroll
    for (int ss = 0; ss < NS; ++ss) {
        float r = qv * bf2f(ksb[(size_t)(b * NS + ss) * 512 + h * 64 + lane]);
#pragma unroll
        for (int off = 32; off; off >>= 1) r += __shfl_xor(r, off);
        if (lane == ss) sc = r;
    }
    float val = (lane < NS)
        ? sc + bias_s[((size_t)(b * HH + h) * LQ + q) * NS + lane]
        : -1e30f;

    float m = val;
#pragma unroll
    for (int off = 32; off; off >>= 1) m = fmaxf(m, __shfl_xor(m, off));
    float p = __expf(val - m);
    float sum = p;
#pragma unroll
    for (int off = 32; off; off >>= 1) sum += __shfl_xor(sum, off);
    p /= sum;

    const int tcl = (lane < NS) ? lane : (NS - 1);
    const float* gb = gab + (size_t)(b * HH + h) * NS * NS;
    float g = 0.f;
#pragma unroll
    for (int ss = 0; ss < NS; ++ss) {
        float ps = __shfl(p, ss);
        g += ps * gb[ss * NS + tcl];
    }
    float val2 = val - 0.5f * g * g;

    float m2 = val2;
#pragma unroll
    for (int off = 32; off; off >>= 1) m2 = fmaxf(m2, __shfl_xor(m2, off));
    float a = __expf(val2 - m2);
    float sum2 = a;
#pragma unroll
    for (int off = 32; off; off >>= 1) sum2 += __shfl_xor(sum2, off);
    a /= sum2;

    if (lane < NS)
        attns[((size_t)(b * HH + h) * LQ + q) * NS + lane] = a;

    float ctx = 0.f;
#pragma unroll
    for (int ss = 0; ss < NS; ++ss) {
        float as = __shfl(a, ss);
        ctx += as * bf2f(vsb[(size_t)(b * NS + ss) * 512 + h * 64 + lane]);
    }
    ctxs[(size_t)(b * LQ + q) * 512 + h * 64 + lane] = f2bf(ctx);
}

// ---------------- word-level attention via MFMA, bias staged in LDS ----------------
// grid 3072: bid -> s(24) | qt(4) | h(8) | b(4). 4 waves, wave = 16 q rows.
__global__ __launch_bounds__(256) void word_attn_mfma(
    const unsigned short* __restrict__ qwb,   // [B*LQ, 512] bf16
    const unsigned short* __restrict__ kwb,   // [B*NS*NT, 512] bf16
    const unsigned short* __restrict__ vwbT,  // [512, B*NS*NT] bf16 (transposed)
    const float* __restrict__ bias_w,         // [B,NS,H,LQ,NT] fp32
    const float* __restrict__ attns,          // [B,H,LQ,NS] fp32
    unsigned short* __restrict__ part)        // [24][B][H][LQ][64] bf16
{
    __shared__ __align__(16) float bias_lds[64 * 128];          // 32 KB
    __shared__ __align__(16) unsigned short P_lds[4][16][136];  // 17.4 KB
    const int bid = blockIdx.x;
    const int s  = bid % 24;
    const int r_ = bid / 24;
    const int qt = r_ & 3;
    const int h  = (r_ >> 2) & 7;
    const int b  = r_ >> 5;
    const int tid = threadIdx.x;
    const int wv = tid >> 6;
    const int l  = tid & 63;
    const int lr = l & 15;
    const int lg = l >> 4;
    const int q0 = qt * 64 + wv * 16;
    const int MW = BB * NS * NT;   // 12288

    // ---- stage bias tile [64q x 128t] fp32 (contiguous 32 KB) via global_load_lds ----
    const float* bsrc = bias_w + ((((size_t)(b * NS + s) * HH + h) * LQ) + qt * 64) * NT;
#pragma unroll
    for (int it = 0; it < 8; ++it) {
        const int chunk = it * 4 + wv;             // 32 chunks of 256 floats (1 KB)
        gload_lds16(bsrc + chunk * 256 + l * 4, bias_lds + chunk * 256);
    }

    const unsigned short* qbase = qwb + (size_t)(b * LQ + q0 + lr) * 512 + h * 64 + lg * 8;
    short8v aq0 = *(const short8v*)(qbase);
    short8v aq1 = *(const short8v*)(qbase + 32);

    f32x4 out0 = {0.f,0.f,0.f,0.f}, out1 = out0, out2 = out0, out3 = out0;

    // ---- scores: S[16q x 128t] = Q @ K^T ----
    f32x4 sc[8];
    const unsigned short* kbase = kwb + (size_t)((b * NS + s) * NT + lr) * 512 + h * 64 + lg * 8;
#pragma unroll
    for (int n = 0; n < 8; ++n) {
        const unsigned short* kp = kbase + (size_t)n * 16 * 512;
        short8v bk0 = *(const short8v*)(kp);
        short8v bk1 = *(const short8v*)(kp + 32);
        f32x4 z = {0.f,0.f,0.f,0.f};
        z = __builtin_amdgcn_mfma_f32_16x16x32_bf16(aq0, bk0, z, 0, 0, 0);
        sc[n] = __builtin_amdgcn_mfma_f32_16x16x32_bf16(aq1, bk1, z, 0, 0, 0);
    }
    __syncthreads();   // bias_lds staged (vmcnt drained), cross-wave chunks visible

    // ---- bias + softmax + attns renorm (rows q = q0 + lg*4 + reg) ----
#pragma unroll
    for (int reg = 0; reg < 4; ++reg) {
        const int row = wv * 16 + lg * 4 + reg;    // local bias row
        const float* br = bias_lds + row * 128 + lr;
        float v0 = sc[0][reg] * 0.125f + br[  0];
        float v1 = sc[1][reg] * 0.125f + br[ 16];
        float v2 = sc[2][reg] * 0.125f + br[ 32];
        float v3 = sc[3][reg] * 0.125f + br[ 48];
        float v4 = sc[4][reg] * 0.125f + br[ 64];
        float v5 = sc[5][reg] * 0.125f + br[ 80];
        float v6 = sc[6][reg] * 0.125f + br[ 96];
        float v7 = sc[7][reg] * 0.125f + br[112];
        float mx = fmaxf(fmaxf(fmaxf(v0, v1), fmaxf(v2, v3)),
                         fmaxf(fmaxf(v4, v5), fmaxf(v6, v7)));
        mx = fmaxf(mx, __shfl_xor(mx, 1));
        mx = fmaxf(mx, __shfl_xor(mx, 2));
        mx = fmaxf(mx, __shfl_xor(mx, 4));
        mx = fmaxf(mx, __shfl_xor(mx, 8));
        v0 = __expf(v0 - mx); v1 = __expf(v1 - mx); v2 = __expf(v2 - mx); v3 = __expf(v3 - mx);
        v4 = __expf(v4 - mx); v5 = __expf(v5 - mx); v6 = __expf(v6 - mx); v7 = __expf(v7 - mx);
        float sm = ((v0 + v1) + (v2 + v3)) + ((v4 + v5) + (v6 + v7));
        sm += __shfl_xor(sm, 1);
        sm += __shfl_xor(sm, 2);
        sm += __shfl_xor(sm, 4);
        sm += __shfl_xor(sm, 8);
        float at = attns[((size_t)(b * HH + h) * LQ + q0 + lg * 4 + reg) * NS + s];
        float fac = at / sm;
        const int qrow = lg * 4 + reg;
        P_lds[wv][qrow][  0 + lr] = f2bf(v0 * fac);
        P_lds[wv][qrow][ 16 + lr] = f2bf(v1 * fac);
        P_lds[wv][qrow][ 32 + lr] = f2bf(v2 * fac);
        P_lds[wv][qrow][ 48 + lr] = f2bf(v3 * fac);
        P_lds[wv][qrow][ 64 + lr] = f2bf(v4 * fac);
        P_lds[wv][qrow][ 80 + lr] = f2bf(v5 * fac);
        P_lds[wv][qrow][ 96 + lr] = f2bf(v6 * fac);
        P_lds[wv][qrow][112 + lr] = f2bf(v7 * fac);
    }
    // ---- PV: out[16q x 64d] = P @ V ----
    const unsigned short* vb = vwbT + (size_t)(h * 64 + lr) * MW + (size_t)(b * NS + s) * NT + lg * 8;
#pragma unroll
    for (int ks = 0; ks < 4; ++ks) {
        short8v pa = *(const short8v*)&P_lds[wv][lr][ks * 32 + lg * 8];
        const unsigned short* vk = vb + ks * 32;
        short8v bv0 = *(const short8v*)(vk);
        short8v bv1 = *(const short8v*)(vk + (size_t)16 * MW);
        short8v bv2 = *(const short8v*)(vk + (size_t)32 * MW);
        short8v bv3 = *(const short8v*)(vk + (size_t)48 * MW);
        out0 = __builtin_amdgcn_mfma_f32_16x16x32_bf16(pa, bv0, out0, 0, 0, 0);
        out1 = __builtin_amdgcn_mfma_f32_16x16x32_bf16(pa, bv1, out1, 0, 0, 0);
        out2 = __builtin_amdgcn_mfma_f32_16x16x32_bf16(pa, bv2, out2, 0, 0, 0);
        out3 = __builtin_amdgcn_mfma_f32_16x16x32_bf16(pa, bv3, out3, 0, 0, 0);
    }
    unsigned short* pp = part + ((((size_t)s * BB + b) * HH + h) * LQ) * 64;
#pragma unroll
    for (int reg = 0; reg < 4; ++reg) {
        const size_t ro = (size_t)(q0 + lg * 4 + reg) * 64 + lr;
        pp[ro +  0] = f2bf(out0[reg]);
        pp[ro + 16] = f2bf(out1[reg]);
        pp[ro + 32] = f2bf(out2[reg]);
        pp[ro + 48] = f2bf(out3[reg]);
    }
}

// ---------------- reduce 24 bf16 s-partials -> ctxw bf16 [B,LQ,512] ----------------
__global__ __launch_bounds__(256) void reduce_part(
    const unsigned short* __restrict__ part, unsigned short* __restrict__ ctxw)
{
    int idx = blockIdx.x * 256 + threadIdx.x;   // 524288
    int d = idx & 63;
    int q = (idx >> 6) & 255;
    int h = (idx >> 14) & 7;
    int b = idx >> 17;
    size_t o = ((((size_t)b * HH + h) * LQ) + q) * 64 + d;
    const size_t stride = (size_t)BB * HH * LQ * 64;
    float acc = 0.f;
#pragma unroll
    for (int sp = 0; sp < 24; ++sp) acc += bf2f(part[o + sp * stride]);
    ctxw[((size_t)(b * LQ + q)) * 512 + h * 64 + d] = f2bf(acc);
}

extern "C" void kernel_launch(void* const* d_in, const int* in_sizes, int n_in,
                              void* d_out, int out_size, void* d_ws, size_t ws_size,
                              hipStream_t stream) {
    const float* q_in   = (const float*)d_in[0];
    const float* k_s    = (const float*)d_in[1];
    const float* v_s    = (const float*)d_in[2];
    const float* k_w    = (const float*)d_in[3];
    const float* v_w    = (const float*)d_in[4];
    const float* bias_w = (const float*)d_in[5];
    const float* bias_s = (const float*)d_in[6];
    const float* gab    = (const float*)d_in[7];
    const float* wq_s = (const float*)d_in[8];
    const float* wk_s = (const float*)d_in[9];
    const float* wv_s = (const float*)d_in[10];
    const float* wq_w = (const float*)d_in[11];
    const float* wk_w = (const float*)d_in[12];
    const float* wv_w = (const float*)d_in[13];
    const float* fcs_w = (const float*)d_in[14];
    const float* fcw_w = (const float*)d_in[15];
    const float* bq_s = (const float*)d_in[16];
    const float* bk_s = (const float*)d_in[17];
    const float* bv_s = (const float*)d_in[18];
    const float* bq_w = (const float*)d_in[19];
    const float* bk_w = (const float*)d_in[20];
    const float* bv_w = (const float*)d_in[21];
    const float* fcs_b = (const float*)d_in[22];
    const float* fcw_b = (const float*)d_in[23];
    const float* fco_w = (const float*)d_in[24];
    const float* fco_b = (const float*)d_in[25];
    float* out = (float*)d_out;

    // ---- workspace layout ----
    float* attns = (float*)d_ws;                               // 196608 f32
    unsigned short* base = (unsigned short*)(attns + 196608);
    unsigned short* ctxs  = base;                              // 524288
    unsigned short* ctxw  = ctxs  + 524288;                    // 524288
    unsigned short* qb    = ctxw  + 524288;                    // 524288 } cat aliases
    unsigned short* qs_b  = qb    + 524288;                    // 524288 }
    unsigned short* ks_in = qs_b  + 524288;                    // 49152
    unsigned short* vs_in = ks_in + 49152;                     // 49152
    unsigned short* ksp   = vs_in + 49152;                     // 49152
    unsigned short* vsp   = ksp   + 49152;                     // 49152
    unsigned short* qwb   = vsp   + 49152;                     // 524288
    unsigned short* kwb   = qwb   + 524288;                    // 6291456
    unsigned short* vwbT  = kwb   + 6291456;                   // 6291456
    unsigned short* kw_in = vwbT  + 6291456;                   // 6291456 } part aliases
    unsigned short* vw_in = kw_in + 6291456;                   // 6291456 }
    unsigned short* wts   = vw_in + 6291456;                   // 2621440 (9 transposed weights)
    unsigned short* part = kw_in;  // [24][B][H][LQ][64] bf16 (kw_in/vw_in dead after projections)
    unsigned short* cat = qb;      // 1048576 (qb/qs_b dead after sent_attn)

    WTArgs wa;
    const float* wsrc[9] = {wq_s, wk_s, wv_s, wq_w, wk_w, wv_w, fcs_w, fcw_w, fco_w};
    for (int i = 0; i < 9; ++i) {
        wa.w[i]  = wsrc[i];
        wa.wt[i] = wts + (size_t)i * 262144;
        wa.K[i]  = (i == 8) ? 1024 : 512;
    }
    unsigned short* wtq_s = wts;
    unsigned short* wtk_s = wts + 262144;
    unsigned short* wtv_s = wts + 2 * 262144;
    unsigned short* wtq_w = wts + 3 * 262144;
    unsigned short* wtk_w = wts + 4 * 262144;
    unsigned short* wtv_w = wts + 5 * 262144;
    unsigned short* wtfcs = wts + 6 * 262144;
    unsigned short* wtfcw = wts + 7 * 262144;
    unsigned short* wtfco = wts + 8 * 262144;

    dim3 blk(256);
    // input casts + weight transposes
    cast5<<<6448, blk, 0, stream>>>(q_in, k_s, v_s, k_w, v_w, qb, ks_in, vs_in, kw_in, vw_in);
    wtrans<<<dim3(16, 8, 9), blk, 0, stream>>>(wa);
    // batched projections (bf16 MFMA): z0=k_w (96 mblocks), z1=q_s, z2=q_w, z3=k_s, z4=v_s
    GB g1;
    g1.A[0] = kw_in; g1.WT[0] = wtk_w; g1.bias[0] = bk_w; g1.C[0] = kwb;  g1.M[0] = 12288; g1.ldc[0] = 512; g1.coloff[0] = 0;
    g1.A[1] = qb;    g1.WT[1] = wtq_s; g1.bias[1] = bq_s; g1.C[1] = qs_b; g1.M[1] = 1024;  g1.ldc[1] = 512; g1.coloff[1] = 0;
    g1.A[2] = qb;    g1.WT[2] = wtq_w; g1.bias[2] = bq_w; g1.C[2] = qwb;  g1.M[2] = 1024;  g1.ldc[2] = 512; g1.coloff[2] = 0;
    g1.A[3] = ks_in; g1.WT[3] = wtk_s; g1.bias[3] = bk_s; g1.C[3] = ksp;  g1.M[3] = 96;    g1.ldc[3] = 512; g1.coloff[3] = 0;
    g1.A[4] = vs_in; g1.WT[4] = wtv_s; g1.bias[4] = bv_s; g1.C[4] = vsp;  g1.M[4] = 96;    g1.ldc[4] = 512; g1.coloff[4] = 0;
    gemm_batch<<<dim3(96, 4, 5), blk, 0, stream>>>(g1);
    // V projection with transposed output
    gemm_mfma<2, 512><<<dim3(96, 4), blk, 0, stream>>>(vw_in, wtv_w, bv_w, vwbT, 12288, 0, 0);
    // sentence attention
    sent_attn<<<2048, blk, 0, stream>>>(qs_b, ksp, vsp, bias_s, gab, attns, ctxs);
    // word attention (MFMA, bias in LDS, 24 partials) + reduce
    word_attn_mfma<<<3072, blk, 0, stream>>>(qwb, kwb, vwbT, bias_w, attns, part);
    reduce_part<<<2048, blk, 0, stream>>>(part, ctxw);
    // batched fc projections
    GB g2;
    g2.A[0] = ctxs; g2.WT[0] = wtfcs; g2.bias[0] = fcs_b; g2.C[0] = cat; g2.M[0] = 1024; g2.ldc[0] = 1024; g2.coloff[0] = 0;
    g2.A[1] = ctxw; g2.WT[1] = wtfcw; g2.bias[1] = fcw_b; g2.C[1] = cat; g2.M[1] = 1024; g2.ldc[1] = 1024; g2.coloff[1] = 512;
    g2.A[2] = ctxs; g2.WT[2] = wtfcs; g2.bias[2] = fcs_b; g2.C[2] = cat; g2.M[2] = 0;    g2.ldc[2] = 1024; g2.coloff[2] = 0;
    g2.A[3] = g2.A[2]; g2.WT[3] = g2.WT[2]; g2.bias[3] = g2.bias[2]; g2.C[3] = g2.C[2]; g2.M[3] = 0; g2.ldc[3] = 1024; g2.coloff[3] = 0;
    g2.A[4] = g2.A[2]; g2.WT[4] = g2.WT[2]; g2.bias[4] = g2.bias[2]; g2.C[4] = g2.C[2]; g2.M[4] = 0; g2.ldc[4] = 1024; g2.coloff[4] = 0;
    gemm_batch<<<dim3(8, 4, 2), blk, 0, stream>>>(g2);
    // final projection
    gemm_mfma<0, 1024><<<dim3(8, 4), blk, 0, stream>>>(cat, wtfco, fco_b, out, 1024, 512, 0);
}

// Round 7
// 369.808 us; speedup vs baseline: 4.5009x; 1.0067x over previous
//
#include <hip/hip_runtime.h>
#include <hip/hip_bf16.h>
#include <cstddef>

#define BB 4
#define LQ 256
#define NS 24
#define NT 128
#define DD 512
#define HH 8
#define DKK 64
// scale = DK^-0.5 = 0.125

typedef short short8v __attribute__((ext_vector_type(8)));   // 8 bf16 in 4 VGPRs
typedef float f32x4 __attribute__((ext_vector_type(4)));

__device__ __forceinline__ unsigned short f2bf(float f) {
    unsigned u = __float_as_uint(f);
    return (unsigned short)((u + 0x7fffu + ((u >> 16) & 1u)) >> 16);
}
__device__ __forceinline__ float bf2f(unsigned short u) {
    return __uint_as_float(((unsigned)u) << 16);
}
__device__ __forceinline__ void gload_lds16(const void* g, void* l) {
    __builtin_amdgcn_global_load_lds(
        (const __attribute__((address_space(1))) void*)g,
        (__attribute__((address_space(3))) void*)l, 16, 0, 0);
}

// ---------------- merged: input casts (blocks 0..6447) + weight transpose (6448..7599) ----
struct CWArgs {
    const float* cq; const float* cks; const float* cvs; const float* ckw; const float* cvw;
    unsigned short *dq, *dks, *dvs, *dkw, *dvw;
    const float* w[9];
    unsigned short* wt[9];
    int K[9];
};
__global__ __launch_bounds__(256) void cast_wtrans(CWArgs a) {
    __shared__ float T[64][65];
    const int bid = blockIdx.x;
    if (bid < 6448) {
        int t = bid * 256 + threadIdx.x;   // each thread: 8 elements
        const float* src; unsigned short* dst; size_t i;
        if (t < 65536)        { src = a.cq;  dst = a.dq;  i = (size_t)t * 8; }
        else if (t < 71680)   { src = a.cks; dst = a.dks; i = (size_t)(t - 65536) * 8; }
        else if (t < 77824)   { src = a.cvs; dst = a.dvs; i = (size_t)(t - 71680) * 8; }
        else if (t < 864256)  { src = a.ckw; dst = a.dkw; i = (size_t)(t - 77824) * 8; }
        else                  { src = a.cvw; dst = a.dvw; i = (size_t)(t - 864256) * 8; }
        float4 x = *(const float4*)(src + i);
        float4 y = *(const float4*)(src + i + 4);
        short8v o;
        o[0] = f2bf(x.x); o[1] = f2bf(x.y); o[2] = f2bf(x.z); o[3] = f2bf(x.w);
        o[4] = f2bf(y.x); o[5] = f2bf(y.y); o[6] = f2bf(y.z); o[7] = f2bf(y.w);
        *(short8v*)(dst + i) = o;
        return;
    }
    const int r = bid - 6448;          // 0..1151
    const int widx = r >> 7;           // 0..8
    const int kt = (r & 127) >> 3;     // 0..15
    const int nt = r & 7;              // 0..7
    const int K = a.K[widx];
    if (kt * 64 >= K) return;
    const float* W = a.w[widx];
    unsigned short* WT = a.wt[widx];
    const int tx = threadIdx.x & 63, ty = threadIdx.x >> 6;
    const int k0 = kt * 64, n0 = nt * 64;
#pragma unroll
    for (int rr = 0; rr < 16; ++rr)
        T[ty * 16 + rr][tx] = W[(size_t)(k0 + ty * 16 + rr) * 512 + n0 + tx];
    __syncthreads();
#pragma unroll
    for (int rr = 0; rr < 16; ++rr)
        WT[(size_t)(n0 + ty * 16 + rr) * K + k0 + tx] = f2bf(T[tx][ty * 16 + rr]);
}

// ---------------- LDS-staged MFMA GEMM core (128x128 tile, BK=32, 4 waves) ----------------
// MODE 0: f32 out; MODE 1: bf16 out; MODE 2: bf16 transposed out CT[N][M] (M%128==0).
template<int MODE, int K>
__device__ __forceinline__ void gemm_core(
    const unsigned short* __restrict__ A, const unsigned short* __restrict__ WT,
    const float* __restrict__ bias, void* __restrict__ Cv, int M, int ldc, int coloff,
    int bx, int by)
{
    __shared__ __align__(16) unsigned short Alds[128 * 32];
    __shared__ __align__(16) unsigned short Blds[128 * 32];
    __shared__ __align__(16) unsigned short Tt[(MODE == 2) ? 128 * 138 : 64];
    const int tid = threadIdx.x;
    const int wv = tid >> 6, l = tid & 63;
    const int lr = l & 15, lg = l >> 4;
    const int wr = wv >> 1, wc = wv & 1;
    const int bm = bx * 128, bn = by * 128;

    const int srl = l >> 2;      // 0..15
    const int sc  = l & 3;       // dest chunk
    f32x4 acc[4][4];
#pragma unroll
    for (int i = 0; i < 4; ++i)
#pragma unroll
        for (int j = 0; j < 4; ++j) acc[i][j] = (f32x4){0.f, 0.f, 0.f, 0.f};

    for (int k0 = 0; k0 < K; k0 += 32) {
#pragma unroll
        for (int j = 0; j < 2; ++j) {
            const int r = wv * 32 + j * 16 + srl;
            const int cs = sc ^ ((r >> 1) & 3);
            int ra = bm + r; if (ra >= M) ra = M - 1;
            gload_lds16(A + (size_t)ra * K + k0 + cs * 8, Alds + (wv * 32 + j * 16) * 32);
            gload_lds16(WT + (size_t)(bn + r) * K + k0 + cs * 8, Blds + (wv * 32 + j * 16) * 32);
        }
        __syncthreads();
        short8v af[4], bf[4];
#pragma unroll
        for (int mf = 0; mf < 4; ++mf) {
            const int row = wr * 64 + mf * 16 + lr;
            af[mf] = *(const short8v*)(Alds + row * 32 + (lg ^ ((row >> 1) & 3)) * 8);
        }
#pragma unroll
        for (int nf = 0; nf < 4; ++nf) {
            const int row = wc * 64 + nf * 16 + lr;
            bf[nf] = *(const short8v*)(Blds + row * 32 + (lg ^ ((row >> 1) & 3)) * 8);
        }
#pragma unroll
        for (int mf = 0; mf < 4; ++mf)
#pragma unroll
            for (int nf = 0; nf < 4; ++nf)
                acc[mf][nf] = __builtin_amdgcn_mfma_f32_16x16x32_bf16(af[mf], bf[nf], acc[mf][nf], 0, 0, 0);
        __syncthreads();
    }

    float bv[4];
#pragma unroll
    for (int nf = 0; nf < 4; ++nf) bv[nf] = bias[bn + wc * 64 + nf * 16 + lr];

    if constexpr (MODE == 0) {
        float* C = (float*)Cv;
#pragma unroll
        for (int mf = 0; mf < 4; ++mf)
#pragma unroll
            for (int reg = 0; reg < 4; ++reg) {
                const int row = bm + wr * 64 + mf * 16 + lg * 4 + reg;
                if (row < M) {
#pragma unroll
                    for (int nf = 0; nf < 4; ++nf)
                        C[(size_t)row * ldc + coloff + bn + wc * 64 + nf * 16 + lr] = acc[mf][nf][reg] + bv[nf];
                }
            }
    } else if constexpr (MODE == 1) {
        unsigned short* C = (unsigned short*)Cv;
#pragma unroll
        for (int mf = 0; mf < 4; ++mf)
#pragma unroll
            for (int reg = 0; reg < 4; ++reg) {
                const int row = bm + wr * 64 + mf * 16 + lg * 4 + reg;
                if (row < M) {
#pragma unroll
                    for (int nf = 0; nf < 4; ++nf)
                        C[(size_t)row * ldc + coloff + bn + wc * 64 + nf * 16 + lr] = f2bf(acc[mf][nf][reg] + bv[nf]);
                }
            }
    } else {
        // transposed bf16 out CT[N][M]
#pragma unroll
        for (int nf = 0; nf < 4; ++nf)
#pragma unroll
            for (int mf = 0; mf < 4; ++mf)
#pragma unroll
                for (int reg = 0; reg < 4; ++reg)
                    Tt[(size_t)(wc * 64 + nf * 16 + lr) * 138 + wr * 64 + mf * 16 + lg * 4 + reg] =
                        f2bf(acc[mf][nf][reg] + bv[nf]);
        __syncthreads();
        unsigned short* CT = (unsigned short*)Cv;
        const int rown = tid >> 3;          // 0..31
        const int c8 = (tid & 7) * 8;       // 0..56
#pragma unroll
        for (int it = 0; it < 4; ++it) {
            const int n = it * 32 + rown;
#pragma unroll
            for (int half = 0; half < 2; ++half) {
                const int m = half * 64 + c8;
                *(short8v*)(CT + (size_t)(bn + n) * M + bm + m) = *(const short8v*)(Tt + (size_t)n * 138 + m);
            }
        }
    }
}

template<int MODE, int K>
__global__ __launch_bounds__(256) void gemm_mfma(
    const unsigned short* __restrict__ A, const unsigned short* __restrict__ WT,
    const float* __restrict__ bias, void* __restrict__ Cv, int M, int ldc, int coloff)
{
    gemm_core<MODE, K>(A, WT, bias, Cv, M, ldc, coloff, blockIdx.x, blockIdx.y);
}

// ---------------- batched MODE1 K=512 GEMMs (z-dim selects problem) ----------------
struct GB {
    const unsigned short* A[5];
    const unsigned short* WT[5];
    const float* bias[5];
    unsigned short* C[5];
    int M[5];
    int ldc[5];
    int coloff[5];
};
__global__ __launch_bounds__(256) void gemm_batch(GB g) {
    const int z = blockIdx.z;
    const int M = g.M[z];
    if ((int)blockIdx.x * 128 >= M) return;
    gemm_core<1, 512>(g.A[z], g.WT[z], g.bias[z], g.C[z], M, g.ldc[z], g.coloff[z],
                      blockIdx.x, blockIdx.y);
}

// ---------------- sentence-level graph attention (bf16 in, fp32 math) ----------------
__global__ __launch_bounds__(256) void sent_attn(
    const unsigned short* __restrict__ qs, const unsigned short* __restrict__ ksb,
    const unsigned short* __restrict__ vsb, const float* __restrict__ bias_s,
    const float* __restrict__ gab, float* __restrict__ attns,
    unsigned short* __restrict__ ctxs)
{
    const int wid = blockIdx.x * 4 + (threadIdx.x >> 6);
    const int lane = threadIdx.x & 63;
    const int q = wid & (LQ - 1);
    const int bh = wid >> 8;
    const int h = bh & 7;
    const int b = bh >> 3;

    float qv = bf2f(qs[(size_t)(b * LQ + q) * 512 + h * 64 + lane]) * 0.125f;

    float sc = 0.f;
#pragma unroll
    for (int ss = 0; ss < NS; ++ss) {
        float r = qv * bf2f(ksb[(size_t)(b * NS + ss) * 512 + h * 64 + lane]);
#pragma unroll
        for (int off = 32; off; off >>= 1) r += __shfl_xor(r, off);
        if (lane == ss) sc = r;
    }
    float val = (lane < NS)
        ? sc + bias_s[((size_t)(b * HH + h) * LQ + q) * NS + lane]
        : -1e30f;

    float m = val;
#pragma unroll
    for (int off = 32; off; off >>= 1) m = fmaxf(m, __shfl_xor(m, off));
    float p = __expf(val - m);
    float sum = p;
#pragma unroll
    for (int off = 32; off; off >>= 1) sum += __shfl_xor(sum, off);
    p /= sum;

    const int tcl = (lane < NS) ? lane : (NS - 1);
    const float* gb = gab + (size_t)(b * HH + h) * NS * NS;
    float g = 0.f;
#pragma unroll
    for (int ss = 0; ss < NS; ++ss) {
        float ps = __shfl(p, ss);
        g += ps * gb[ss * NS + tcl];
    }
    float val2 = val - 0.5f * g * g;

    float m2 = val2;
#pragma unroll
    for (int off = 32; off; off >>= 1) m2 = fmaxf(m2, __shfl_xor(m2, off));
    float a = __expf(val2 - m2);
    float sum2 = a;
#pragma unroll
    for (int off = 32; off; off >>= 1) sum2 += __shfl_xor(sum2, off);
    a /= sum2;

    if (lane < NS)
        attns[((size_t)(b * HH + h) * LQ + q) * NS + lane] = a;

    float ctx = 0.f;
#pragma unroll
    for (int ss = 0; ss < NS; ++ss) {
        float as = __shfl(a, ss);
        ctx += as * bf2f(vsb[(size_t)(b * NS + ss) * 512 + h * 64 + lane]);
    }
    ctxs[(size_t)(b * LQ + q) * 512 + h * 64 + lane] = f2bf(ctx);
}

// ---------------- word-level attention via MFMA, barrier-free (per-wave LDS) ----------
// grid 3072: bid -> s(24) | qt(4) | h(8) | b(4). 4 waves, wave = 16 q rows, all LDS per-wave.
__global__ __launch_bounds__(256) void word_attn_mfma(
    const unsigned short* __restrict__ qwb,   // [B*LQ, 512] bf16
    const unsigned short* __restrict__ kwb,   // [B*NS*NT, 512] bf16
    const unsigned short* __restrict__ vwbT,  // [512, B*NS*NT] bf16 (transposed)
    const float* __restrict__ bias_w,         // [B,NS,H,LQ,NT] fp32
    const float* __restrict__ attns,          // [B,H,LQ,NS] fp32
    unsigned short* __restrict__ part)        // [24][B][H][LQ][64] bf16
{
    __shared__ __align__(16) float bias_lds[64 * 128];          // 32 KB, rows wv*16.. per wave
    __shared__ __align__(16) unsigned short P_lds[4][16][136];  // 17.4 KB, per-wave slice
    const int bid = blockIdx.x;
    const int s  = bid % 24;
    const int r_ = bid / 24;
    const int qt = r_ & 3;
    const int h  = (r_ >> 2) & 7;
    const int b  = r_ >> 5;
    const int tid = threadIdx.x;
    const int wv = tid >> 6;
    const int l  = tid & 63;
    const int lr = l & 15;
    const int lg = l >> 4;
    const int q0 = qt * 64 + wv * 16;
    const int MW = BB * NS * NT;   // 12288

    // ---- each wave stages ITS OWN 16 bias rows (8 KB contiguous) via global_load_lds ----
    const float* bsrc = bias_w + ((((size_t)(b * NS + s) * HH + h) * LQ) + qt * 64) * NT;
#pragma unroll
    for (int it = 0; it < 8; ++it) {
        const int chunk = wv * 8 + it;             // rows wv*16 .. wv*16+15
        gload_lds16(bsrc + chunk * 256 + l * 4, bias_lds + chunk * 256);
    }

    const unsigned short* qbase = qwb + (size_t)(b * LQ + q0 + lr) * 512 + h * 64 + lg * 8;
    short8v aq0 = *(const short8v*)(qbase);
    short8v aq1 = *(const short8v*)(qbase + 32);

    f32x4 out0 = {0.f,0.f,0.f,0.f}, out1 = out0, out2 = out0, out3 = out0;

    // ---- scores: S[16q x 128t] = Q @ K^T ----
    f32x4 sc[8];
    const unsigned short* kbase = kwb + (size_t)((b * NS + s) * NT + lr) * 512 + h * 64 + lg * 8;
#pragma unroll
    for (int n = 0; n < 8; ++n) {
        const unsigned short* kp = kbase + (size_t)n * 16 * 512;
        short8v bk0 = *(const short8v*)(kp);
        short8v bk1 = *(const short8v*)(kp + 32);
        f32x4 z = {0.f,0.f,0.f,0.f};
        z = __builtin_amdgcn_mfma_f32_16x16x32_bf16(aq0, bk0, z, 0, 0, 0);
        sc[n] = __builtin_amdgcn_mfma_f32_16x16x32_bf16(aq1, bk1, z, 0, 0, 0);
    }
    // per-wave: wait for this wave's bias staging (no barrier). VMEM reads may cross (0x20).
    asm volatile("s_waitcnt vmcnt(0)" ::: "memory");
    __builtin_amdgcn_sched_barrier(0x20);

    // ---- bias + softmax + attns renorm (rows q = q0 + lg*4 + reg) ----
#pragma unroll
    for (int reg = 0; reg < 4; ++reg) {
        const int row = wv * 16 + lg * 4 + reg;    // local bias row
        const float* br = bias_lds + row * 128 + lr;
        float v0 = sc[0][reg] * 0.125f + br[  0];
        float v1 = sc[1][reg] * 0.125f + br[ 16];
        float v2 = sc[2][reg] * 0.125f + br[ 32];
        float v3 = sc[3][reg] * 0.125f + br[ 48];
        float v4 = sc[4][reg] * 0.125f + br[ 64];
        float v5 = sc[5][reg] * 0.125f + br[ 80];
        float v6 = sc[6][reg] * 0.125f + br[ 96];
        float v7 = sc[7][reg] * 0.125f + br[112];
        float mx = fmaxf(fmaxf(fmaxf(v0, v1), fmaxf(v2, v3)),
                         fmaxf(fmaxf(v4, v5), fmaxf(v6, v7)));
        mx = fmaxf(mx, __shfl_xor(mx, 1));
        mx = fmaxf(mx, __shfl_xor(mx, 2));
        mx = fmaxf(mx, __shfl_xor(mx, 4));
        mx = fmaxf(mx, __shfl_xor(mx, 8));
        v0 = __expf(v0 - mx); v1 = __expf(v1 - mx); v2 = __expf(v2 - mx); v3 = __expf(v3 - mx);
        v4 = __expf(v4 - mx); v5 = __expf(v5 - mx); v6 = __expf(v6 - mx); v7 = __expf(v7 - mx);
        float sm = ((v0 + v1) + (v2 + v3)) + ((v4 + v5) + (v6 + v7));
        sm += __shfl_xor(sm, 1);
        sm += __shfl_xor(sm, 2);
        sm += __shfl_xor(sm, 4);
        sm += __shfl_xor(sm, 8);
        float at = attns[((size_t)(b * HH + h) * LQ + q0 + lg * 4 + reg) * NS + s];
        float fac = at / sm;
        const int qrow = lg * 4 + reg;
        P_lds[wv][qrow][  0 + lr] = f2bf(v0 * fac);
        P_lds[wv][qrow][ 16 + lr] = f2bf(v1 * fac);
        P_lds[wv][qrow][ 32 + lr] = f2bf(v2 * fac);
        P_lds[wv][qrow][ 48 + lr] = f2bf(v3 * fac);
        P_lds[wv][qrow][ 64 + lr] = f2bf(v4 * fac);
        P_lds[wv][qrow][ 80 + lr] = f2bf(v5 * fac);
        P_lds[wv][qrow][ 96 + lr] = f2bf(v6 * fac);
        P_lds[wv][qrow][112 + lr] = f2bf(v7 * fac);
    }
    // per-wave: P writes visible to own wave's reads (no barrier).
    asm volatile("s_waitcnt lgkmcnt(0)" ::: "memory");
    __builtin_amdgcn_sched_barrier(0x20);

    // ---- PV: out[16q x 64d] = P @ V ----
    const unsigned short* vb = vwbT + (size_t)(h * 64 + lr) * MW + (size_t)(b * NS + s) * NT + lg * 8;
#pragma unroll
    for (int ks = 0; ks < 4; ++ks) {
        short8v pa = *(const short8v*)&P_lds[wv][lr][ks * 32 + lg * 8];
        const unsigned short* vk = vb + ks * 32;
        short8v bv0 = *(const short8v*)(vk);
        short8v bv1 = *(const short8v*)(vk + (size_t)16 * MW);
        short8v bv2 = *(const short8v*)(vk + (size_t)32 * MW);
        short8v bv3 = *(const short8v*)(vk + (size_t)48 * MW);
        out0 = __builtin_amdgcn_mfma_f32_16x16x32_bf16(pa, bv0, out0, 0, 0, 0);
        out1 = __builtin_amdgcn_mfma_f32_16x16x32_bf16(pa, bv1, out1, 0, 0, 0);
        out2 = __builtin_amdgcn_mfma_f32_16x16x32_bf16(pa, bv2, out2, 0, 0, 0);
        out3 = __builtin_amdgcn_mfma_f32_16x16x32_bf16(pa, bv3, out3, 0, 0, 0);
    }
    unsigned short* pp = part + ((((size_t)s * BB + b) * HH + h) * LQ) * 64;
#pragma unroll
    for (int reg = 0; reg < 4; ++reg) {
        const size_t ro = (size_t)(q0 + lg * 4 + reg) * 64 + lr;
        pp[ro +  0] = f2bf(out0[reg]);
        pp[ro + 16] = f2bf(out1[reg]);
        pp[ro + 32] = f2bf(out2[reg]);
        pp[ro + 48] = f2bf(out3[reg]);
    }
}

// ---------------- reduce 24 bf16 s-partials -> ctxw bf16 [B,LQ,512], vectorized ----------
__global__ __launch_bounds__(256) void reduce_part(
    const unsigned short* __restrict__ part, unsigned short* __restrict__ ctxw)
{
    int idx = blockIdx.x * 256 + threadIdx.x;   // 65536 threads x 8 shorts
    int d8 = idx & 7;
    int q  = (idx >> 3) & 255;
    int h  = (idx >> 11) & 7;
    int b  = idx >> 14;
    size_t o = (((((size_t)b * HH + h) * LQ) + q) * 64) + d8 * 8;
    const size_t stride = (size_t)BB * HH * LQ * 64;
    float acc[8] = {};
#pragma unroll
    for (int sp = 0; sp < 24; ++sp) {
        short8v v = *(const short8v*)(part + o + sp * stride);
#pragma unroll
        for (int j = 0; j < 8; ++j) acc[j] += bf2f((unsigned short)v[j]);
    }
    short8v ov;
#pragma unroll
    for (int j = 0; j < 8; ++j) ov[j] = f2bf(acc[j]);
    *(short8v*)(ctxw + ((size_t)(b * LQ + q)) * 512 + h * 64 + d8 * 8) = ov;
}

extern "C" void kernel_launch(void* const* d_in, const int* in_sizes, int n_in,
                              void* d_out, int out_size, void* d_ws, size_t ws_size,
                              hipStream_t stream) {
    const float* q_in   = (const float*)d_in[0];
    const float* k_s    = (const float*)d_in[1];
    const float* v_s    = (const float*)d_in[2];
    const float* k_w    = (const float*)d_in[3];
    const float* v_w    = (const float*)d_in[4];
    const float* bias_w = (const float*)d_in[5];
    const float* bias_s = (const float*)d_in[6];
    const float* gab    = (const float*)d_in[7];
    const float* wq_s = (const float*)d_in[8];
    const float* wk_s = (const float*)d_in[9];
    const float* wv_s = (const float*)d_in[10];
    const float* wq_w = (const float*)d_in[11];
    const float* wk_w = (const float*)d_in[12];
    const float* wv_w = (const float*)d_in[13];
    const float* fcs_w = (const float*)d_in[14];
    const float* fcw_w = (const float*)d_in[15];
    const float* bq_s = (const float*)d_in[16];
    const float* bk_s = (const float*)d_in[17];
    const float* bv_s = (const float*)d_in[18];
    const float* bq_w = (const float*)d_in[19];
    const float* bk_w = (const float*)d_in[20];
    const float* bv_w = (const float*)d_in[21];
    const float* fcs_b = (const float*)d_in[22];
    const float* fcw_b = (const float*)d_in[23];
    const float* fco_w = (const float*)d_in[24];
    const float* fco_b = (const float*)d_in[25];
    float* out = (float*)d_out;

    // ---- workspace layout ----
    float* attns = (float*)d_ws;                               // 196608 f32
    unsigned short* base = (unsigned short*)(attns + 196608);
    unsigned short* ctxs  = base;                              // 524288
    unsigned short* ctxw  = ctxs  + 524288;                    // 524288
    unsigned short* qb    = ctxw  + 524288;                    // 524288 } cat aliases
    unsigned short* qs_b  = qb    + 524288;                    // 524288 }
    unsigned short* ks_in = qs_b  + 524288;                    // 49152
    unsigned short* vs_in = ks_in + 49152;                     // 49152
    unsigned short* ksp   = vs_in + 49152;                     // 49152
    unsigned short* vsp   = ksp   + 49152;                     // 49152
    unsigned short* qwb   = vsp   + 49152;                     // 524288
    unsigned short* kwb   = qwb   + 524288;                    // 6291456
    unsigned short* vwbT  = kwb   + 6291456;                   // 6291456
    unsigned short* kw_in = vwbT  + 6291456;                   // 6291456 } part aliases
    unsigned short* vw_in = kw_in + 6291456;                   // 6291456 }
    unsigned short* wts   = vw_in + 6291456;                   // 2621440 (9 transposed weights)
    unsigned short* part = kw_in;  // [24][B][H][LQ][64] bf16 (kw_in/vw_in dead after projections)
    unsigned short* cat = qb;      // 1048576 (qb/qs_b dead after sent_attn)

    CWArgs cw;
    cw.cq = q_in; cw.cks = k_s; cw.cvs = v_s; cw.ckw = k_w; cw.cvw = v_w;
    cw.dq = qb; cw.dks = ks_in; cw.dvs = vs_in; cw.dkw = kw_in; cw.dvw = vw_in;
    const float* wsrc[9] = {wq_s, wk_s, wv_s, wq_w, wk_w, wv_w, fcs_w, fcw_w, fco_w};
    for (int i = 0; i < 9; ++i) {
        cw.w[i]  = wsrc[i];
        cw.wt[i] = wts + (size_t)i * 262144;
        cw.K[i]  = (i == 8) ? 1024 : 512;
    }
    unsigned short* wtq_s = wts;
    unsigned short* wtk_s = wts + 262144;
    unsigned short* wtv_s = wts + 2 * 262144;
    unsigned short* wtq_w = wts + 3 * 262144;
    unsigned short* wtk_w = wts + 4 * 262144;
    unsigned short* wtv_w = wts + 5 * 262144;
    unsigned short* wtfcs = wts + 6 * 262144;
    unsigned short* wtfcw = wts + 7 * 262144;
    unsigned short* wtfco = wts + 8 * 262144;

    dim3 blk(256);
    // input casts + weight transposes (merged)
    cast_wtrans<<<7600, blk, 0, stream>>>(cw);
    // batched projections (bf16 MFMA): z0=k_w, z1=q_s, z2=q_w, z3=k_s, z4=v_s
    GB g1;
    g1.A[0] = kw_in; g1.WT[0] = wtk_w; g1.bias[0] = bk_w; g1.C[0] = kwb;  g1.M[0] = 12288; g1.ldc[0] = 512; g1.coloff[0] = 0;
    g1.A[1] = qb;    g1.WT[1] = wtq_s; g1.bias[1] = bq_s; g1.C[1] = qs_b; g1.M[1] = 1024;  g1.ldc[1] = 512; g1.coloff[1] = 0;
    g1.A[2] = qb;    g1.WT[2] = wtq_w; g1.bias[2] = bq_w; g1.C[2] = qwb;  g1.M[2] = 1024;  g1.ldc[2] = 512; g1.coloff[2] = 0;
    g1.A[3] = ks_in; g1.WT[3] = wtk_s; g1.bias[3] = bk_s; g1.C[3] = ksp;  g1.M[3] = 96;    g1.ldc[3] = 512; g1.coloff[3] = 0;
    g1.A[4] = vs_in; g1.WT[4] = wtv_s; g1.bias[4] = bv_s; g1.C[4] = vsp;  g1.M[4] = 96;    g1.ldc[4] = 512; g1.coloff[4] = 0;
    gemm_batch<<<dim3(96, 4, 5), blk, 0, stream>>>(g1);
    // V projection with transposed output
    gemm_mfma<2, 512><<<dim3(96, 4), blk, 0, stream>>>(vw_in, wtv_w, bv_w, vwbT, 12288, 0, 0);
    // sentence attention
    sent_attn<<<2048, blk, 0, stream>>>(qs_b, ksp, vsp, bias_s, gab, attns, ctxs);
    // word attention (MFMA, barrier-free) + reduce
    word_attn_mfma<<<3072, blk, 0, stream>>>(qwb, kwb, vwbT, bias_w, attns, part);
    reduce_part<<<256, blk, 0, stream>>>(part, ctxw);
    // batched fc projections
    GB g2;
    g2.A[0] = ctxs; g2.WT[0] = wtfcs; g2.bias[0] = fcs_b; g2.C[0] = cat; g2.M[0] = 1024; g2.ldc[0] = 1024; g2.coloff[0] = 0;
    g2.A[1] = ctxw; g2.WT[1] = wtfcw; g2.bias[1] = fcw_b; g2.C[1] = cat; g2.M[1] = 1024; g2.ldc[1] = 1024; g2.coloff[1] = 512;
    g2.A[2] = ctxs; g2.WT[2] = wtfcs; g2.bias[2] = fcs_b; g2.C[2] = cat; g2.M[2] = 0;    g2.ldc[2] = 1024; g2.coloff[2] = 0;
    g2.A[3] = g2.A[2]; g2.WT[3] = g2.WT[2]; g2.bias[3] = g2.bias[2]; g2.C[3] = g2.C[2]; g2.M[3] = 0; g2.ldc[3] = 1024; g2.coloff[3] = 0;
    g2.A[4] = g2.A[2]; g2.WT[4] = g2.WT[2]; g2.bias[4] = g2.bias[2]; g2.C[4] = g2.C[2]; g2.M[4] = 0; g2.ldc[4] = 1024; g2.coloff[4] = 0;
    gemm_batch<<<dim3(8, 4, 2), blk, 0, stream>>>(g2);
    // final projection
    gemm_mfma<0, 1024><<<dim3(8, 4), blk, 0, stream>>>(cat, wtfco, fco_b, out, 1024, 512, 0);
}